// Round 11
// baseline (2343.330 us; speedup 1.0000x reference)
//
#include <hip/hip_runtime.h>
#include <math.h>
#include <float.h>

#define ZTPB 256
#define ZF_TPB 1024
#define ZBUF 4096
#define ZNB 4096
#define T0KEY 0xC0000000u  // f2key(+2.0f): speculative raw-logit threshold

__device__ __forceinline__ unsigned z_f2key(float f) {
  unsigned u = __float_as_uint(f);
  return (u & 0x80000000u) ? ~u : (u | 0x80000000u);
}
__device__ __forceinline__ float z_key2f(unsigned k) {
  unsigned u = (k & 0x80000000u) ? (k & 0x7FFFFFFFu) : ~k;
  return __uint_as_float(u);
}
// Finite as fp32 AND as both bf16 halves (harness reads output as bf16).
__device__ __forceinline__ float z_dualfinite(float x) {
  unsigned u = __float_as_uint(x);
  if ((u & 0x7F800000u) == 0x7F800000u) u = 0xFF7F0000u;
  return __uint_as_float(u & 0xFFFF0000u);
}

// Shared tail: bitonic sort (wave-coherent low strides), softmax cumsum,
// exact top-k tie boundary, top-p crossing -> cutoff. TPB = ZF_TPB.
__device__ void z_tail(unsigned long long* buf, float* csum, float* wsum,
                       int* s_j0, int* s_c, int n, int k, float r, float p,
                       unsigned long long* cut_out, int tid) {
  const int lane = tid & 63;
  const int wave = tid >> 6;
  int m = 64;
  while (m < n) m <<= 1;
  for (int i = n + tid; i < m; i += ZF_TPB) buf[i] = 0xFFFFFFFFFFFFFFFFull;
  __syncthreads();
  for (int size = 2; size <= m; size <<= 1) {
    for (int stride = size >> 1; stride > 0; stride >>= 1) {
      if (stride >= 32) __syncthreads();
      else __asm__ volatile("" ::: "memory");
      for (int i = tid; i < m; i += ZF_TPB) {
        int j = i ^ stride;
        if (j > i) {
          unsigned long long a = buf[i], bb = buf[j];
          bool up = ((i & size) == 0);
          if (up ? (a > bb) : (a < bb)) { buf[i] = bb; buf[j] = a; }
        }
      }
    }
  }
  __syncthreads();

  const float maxv = z_key2f((unsigned)(buf[n - 1] >> 32)) * r;
  const int i0 = tid << 2;
  float e0 = 0.f, e1 = 0.f, e2 = 0.f, e3 = 0.f;
  if (i0 < n)     e0 = expf(z_key2f((unsigned)(buf[i0] >> 32)) * r - maxv);
  if (i0 + 1 < n) e1 = expf(z_key2f((unsigned)(buf[i0 + 1] >> 32)) * r - maxv);
  if (i0 + 2 < n) e2 = expf(z_key2f((unsigned)(buf[i0 + 2] >> 32)) * r - maxv);
  if (i0 + 3 < n) e3 = expf(z_key2f((unsigned)(buf[i0 + 3] >> 32)) * r - maxv);
  const float lsum = e0 + e1 + e2 + e3;
  float vincl = lsum;
  for (int d = 1; d < 64; d <<= 1) {
    float o = __shfl_up(vincl, d);
    if (lane >= d) vincl += o;
  }
  if (lane == 63) wsum[wave] = vincl;
  __syncthreads();
  if (wave == 0 && lane < 16) {
    float s = wsum[lane];
    for (int d = 1; d < 16; d <<= 1) {
      float o = __shfl_up(s, d);
      if (lane >= d) s += o;
    }
    wsum[lane] = s;
  }
  __syncthreads();
  {
    float rr = (wave > 0 ? wsum[wave - 1] : 0.0f) + (vincl - lsum);
    rr += e0; if (i0 < n)     csum[i0] = rr;
    rr += e1; if (i0 + 1 < n) csum[i0 + 1] = rr;
    rr += e2; if (i0 + 2 < n) csum[i0 + 2] = rr;
    rr += e3; if (i0 + 3 < n) csum[i0 + 3] = rr;
  }
  __syncthreads();

  const int k_eff = (k < n) ? k : n;
  const unsigned vkey = (unsigned)(buf[n - k_eff] >> 32);
  if (tid == 0) { *s_j0 = 0; *s_c = n - 1; }
  __syncthreads();
  for (int i = tid; i < n; i += ZF_TPB) {
    unsigned ki = (unsigned)(buf[i] >> 32);
    if (ki == vkey && (i == 0 || (unsigned)(buf[i - 1] >> 32) != vkey))
      *s_j0 = i;
  }
  __syncthreads();
  const int j0 = *s_j0;
  const float base = (j0 > 0) ? csum[j0 - 1] : 0.0f;
  const float Z = csum[n - 1] - base;
  const float thr = (1.0f - p) * Z;
  for (int i = j0 + tid; i < n; i += ZF_TPB) {
    if (csum[i] - base > thr) atomicMin(s_c, i);
  }
  __syncthreads();
  if (tid == 0) *cut_out = buf[*s_c];
}

// K0: zero per-row counters and flags.
__global__ void z_init(unsigned* __restrict__ cntp, unsigned* __restrict__ flagp,
                       int B) {
  int i = blockIdx.x * blockDim.x + threadIdx.x;
  if (i < B) { cntp[i] = 0u; flagp[i] = 0u; }
}

// K1: streaming ballot-compaction of raw keys >= T0KEY. No LDS, no hist.
__global__ __launch_bounds__(ZTPB) void z_gather(
    const float* __restrict__ logits, unsigned* __restrict__ cntp,
    unsigned* __restrict__ flagp, unsigned long long* __restrict__ gcand,
    int V4) {
  const int row = blockIdx.y;
  const int i = blockIdx.x * ZTPB + threadIdx.x;
  const int lane = threadIdx.x & 63;
  const bool inr = (i < V4);
  float4 v = make_float4(0.f, 0.f, 0.f, 0.f);
  if (inr) v = reinterpret_cast<const float4*>(logits)[(size_t)row * V4 + i];
  unsigned long long* gc = gcand + (size_t)row * ZBUF;
  const unsigned keys[4] = {z_f2key(v.x), z_f2key(v.y), z_f2key(v.z),
                            z_f2key(v.w)};
#pragma unroll
  for (int c = 0; c < 4; ++c) {
    const bool pred = inr && (keys[c] >= T0KEY);
    const unsigned long long m = __ballot(pred);
    if (m) {
      const int cnt = __popcll(m);
      const int leader = __ffsll((unsigned long long)m) - 1;
      unsigned base = 0u;
      if (lane == leader) base = atomicAdd(&cntp[row], (unsigned)cnt);
      base = __shfl(base, leader);
      if (pred) {
        const unsigned pos =
            base + (unsigned)__popcll(m & ((1ull << lane) - 1ull));
        if (pos < ZBUF)
          gc[pos] = ((unsigned long long)keys[c] << 32) | (unsigned)(i * 4 + c);
        else
          atomicOr(&flagp[row], 1u);
      }
    }
  }
}

// K2: per-row finish on the speculative candidate set (n>=k guarantees the
// exact top-k is inside). Flags rows needing the exact fallback.
__global__ __launch_bounds__(ZF_TPB) void z_finish(
    const unsigned long long* __restrict__ gcand,
    const unsigned* __restrict__ cntp, unsigned* __restrict__ flagp,
    const float* __restrict__ temps, const int* __restrict__ ks,
    const float* __restrict__ ps, unsigned long long* __restrict__ cutp,
    int V) {
  __shared__ unsigned long long buf[ZBUF];
  __shared__ float csum[ZBUF];
  __shared__ float wsum[16];
  __shared__ int s_j0, s_c;
  const int row = blockIdx.x;
  const int tid = threadIdx.x;
  int k = ks[row];
  if (k < 1) k = 1;
  if (k > V) k = V;
  const unsigned n_raw = cntp[row];
  if (flagp[row] != 0u || n_raw > ZBUF || (int)n_raw < k) {
    if (tid == 0) flagp[row] = 1u;
    return;
  }
  const int n = (int)n_raw;
  const unsigned long long* gc = gcand + (size_t)row * ZBUF;
  for (int i = tid; i < n; i += ZF_TPB) buf[i] = gc[i];
  z_tail(buf, csum, wsum, &s_j0, &s_c, n, k, 1.0f / temps[row], ps[row],
         &cutp[row], tid);
}

// K3: exact multi-level radix-select fallback; only runs for flagged rows.
__global__ __launch_bounds__(ZF_TPB) void z_fallback(
    const float* __restrict__ logits, const unsigned* __restrict__ flagp,
    const float* __restrict__ temps, const int* __restrict__ ks,
    const float* __restrict__ ps, unsigned long long* __restrict__ cutp,
    int V) {
  const int row = blockIdx.x;
  if (flagp[row] == 0u) return;  // fast exit: speculative path succeeded
  union U {
    unsigned sel[2 * ZNB];
    unsigned long long buf[ZBUF];
  };
  __shared__ U sh;
  __shared__ float csum[ZBUF];
  __shared__ float wsum[16];
  __shared__ unsigned s_cnt;
  __shared__ unsigned sh_prefix;
  __shared__ int sh_kk;
  __shared__ int s_j0, s_c;
  const int tid = threadIdx.x;
  const float4* l4 =
      reinterpret_cast<const float4*>(logits + (size_t)row * (size_t)V);
  const int V4 = V >> 2;
  int k = ks[row];
  if (k < 1) k = 1;
  if (k > V) k = V;

  unsigned prefix = 0;
  int kk = k;
  int n_stop = 0;
  for (int lvl = 0; lvl < 3; ++lvl) {
    const int shift = (lvl == 0) ? 20 : (lvl == 1) ? 8 : 0;
    const int nb = (lvl == 2) ? 256 : 4096;
    for (int i = tid; i < 2 * ZNB; i += ZF_TPB) sh.sel[i] = 0;
    __syncthreads();
    if (lvl == 0) {
      for (int i = tid; i < V4; i += ZF_TPB) {
        float4 v = l4[i];
        atomicAdd(&sh.sel[z_f2key(v.x) >> 20], 1u);
        atomicAdd(&sh.sel[z_f2key(v.y) >> 20], 1u);
        atomicAdd(&sh.sel[z_f2key(v.z) >> 20], 1u);
        atomicAdd(&sh.sel[z_f2key(v.w) >> 20], 1u);
      }
    } else {
      const int hs = (lvl == 1) ? 20 : 8;
      const unsigned want = prefix >> hs;
      const unsigned bmask = (unsigned)(nb - 1);
      for (int i = tid; i < V4; i += ZF_TPB) {
        float4 v = l4[i];
        unsigned key;
        key = z_f2key(v.x);
        if ((key >> hs) == want) atomicAdd(&sh.sel[(key >> shift) & bmask], 1u);
        key = z_f2key(v.y);
        if ((key >> hs) == want) atomicAdd(&sh.sel[(key >> shift) & bmask], 1u);
        key = z_f2key(v.z);
        if ((key >> hs) == want) atomicAdd(&sh.sel[(key >> shift) & bmask], 1u);
        key = z_f2key(v.w);
        if ((key >> hs) == want) atomicAdd(&sh.sel[(key >> shift) & bmask], 1u);
      }
    }
    __syncthreads();
    // serial suffix walk (fallback path; clarity over speed)
    if (tid == 0) {
      int acc = 0;
      sh_prefix = prefix;
      sh_kk = kk;
      for (int b = nb - 1; b >= 0; --b) {
        int h = (int)sh.sel[b];
        if (acc + h >= kk) {
          sh_kk = kk - acc;
          sh_prefix = prefix | ((unsigned)b << shift);
          n_stop = 0;  // dummy
          break;
        }
        acc += h;
      }
    }
    __syncthreads();
    const unsigned newpref = sh_prefix;
    const int newkk = sh_kk;
    __syncthreads();
    // count >= bucket floor = (k - kk) + (suffix incl bucket)
    // recompute n_stop = k - kk + (kk - ???) ... simpler: count on the fly:
    prefix = newpref;
    n_stop = (k - kk) + 0;  // placeholder, recomputed below via compact count
    kk = newkk;
    // stop if this level's bucket-floor threshold keeps the candidate
    // set small enough; exactness of k-th is preserved at any stop level.
    // Count candidates cheaply: done in compact below; we optimistically
    // stop at lvl 0 and descend only if compact overflows.
    if (lvl == 0) {
      // try compact with thr = prefix; if too many, continue to lvl 1
      if (tid == 0) s_cnt = 0;
      __syncthreads();
      for (int i = tid; i < V4; i += ZF_TPB) {
        float4 v = l4[i];
        unsigned key;
        key = z_f2key(v.x);
        if (key >= prefix) atomicAdd(&s_cnt, 1u);
        key = z_f2key(v.y);
        if (key >= prefix) atomicAdd(&s_cnt, 1u);
        key = z_f2key(v.z);
        if (key >= prefix) atomicAdd(&s_cnt, 1u);
        key = z_f2key(v.w);
        if (key >= prefix) atomicAdd(&s_cnt, 1u);
      }
      __syncthreads();
      if (s_cnt <= (unsigned)ZBUF) break;
      __syncthreads();
    } else if (lvl == 2) {
      break;
    } else {
      // check lvl-1 count similarly
      if (tid == 0) s_cnt = 0;
      __syncthreads();
      for (int i = tid; i < V4; i += ZF_TPB) {
        float4 v = l4[i];
        unsigned key;
        key = z_f2key(v.x);
        if (key >= prefix) atomicAdd(&s_cnt, 1u);
        key = z_f2key(v.y);
        if (key >= prefix) atomicAdd(&s_cnt, 1u);
        key = z_f2key(v.z);
        if (key >= prefix) atomicAdd(&s_cnt, 1u);
        key = z_f2key(v.w);
        if (key >= prefix) atomicAdd(&s_cnt, 1u);
      }
      __syncthreads();
      if (s_cnt <= (unsigned)ZBUF) break;
      __syncthreads();
    }
  }
  const unsigned thr = prefix;

  if (tid == 0) s_cnt = 0;
  __syncthreads();
  for (int i = tid; i < V4; i += ZF_TPB) {
    float4 v = l4[i];
    const unsigned basei = (unsigned)(i << 2);
    unsigned key;
    key = z_f2key(v.x);
    if (key >= thr) {
      unsigned pos = atomicAdd(&s_cnt, 1u);
      if (pos < ZBUF) sh.buf[pos] = ((unsigned long long)key << 32) | basei;
    }
    key = z_f2key(v.y);
    if (key >= thr) {
      unsigned pos = atomicAdd(&s_cnt, 1u);
      if (pos < ZBUF) sh.buf[pos] = ((unsigned long long)key << 32) | (basei + 1u);
    }
    key = z_f2key(v.z);
    if (key >= thr) {
      unsigned pos = atomicAdd(&s_cnt, 1u);
      if (pos < ZBUF) sh.buf[pos] = ((unsigned long long)key << 32) | (basei + 2u);
    }
    key = z_f2key(v.w);
    if (key >= thr) {
      unsigned pos = atomicAdd(&s_cnt, 1u);
      if (pos < ZBUF) sh.buf[pos] = ((unsigned long long)key << 32) | (basei + 3u);
    }
  }
  __syncthreads();
  int n = (int)s_cnt;
  if (n > ZBUF) n = ZBUF;
  if (n < 1) n = 1;
  z_tail(sh.buf, csum, wsum, &s_j0, &s_c, n, k, 1.0f / temps[row], ps[row],
         &cutp[row], tid);
}

// K4: fat apply on raw keys; scale survivors by r = 1/T. Sole writer of the
// final d_out; dual-finite everywhere.
__global__ void z_apply(const float* __restrict__ logits,
                        const float* __restrict__ temps,
                        const unsigned long long* __restrict__ cutp,
                        float* __restrict__ out, int V4) {
  const int row = blockIdx.y;
  const int i = blockIdx.x * blockDim.x + threadIdx.x;
  if (i >= V4) return;
  const float r = 1.0f / temps[row];
  const unsigned long long cutoff = cutp[row];
  const size_t base = (size_t)row * (size_t)V4 + i;
  float4 v = reinterpret_cast<const float4*>(logits)[base];
  const float NEG = __uint_as_float(0xFF7F0000u);
  const unsigned e = (unsigned)(i << 2);
  unsigned long long k0 = ((unsigned long long)z_f2key(v.x) << 32) | e;
  unsigned long long k1 = ((unsigned long long)z_f2key(v.y) << 32) | (e + 1u);
  unsigned long long k2 = ((unsigned long long)z_f2key(v.z) << 32) | (e + 2u);
  unsigned long long k3 = ((unsigned long long)z_f2key(v.w) << 32) | (e + 3u);
  v.x = (k0 >= cutoff) ? z_dualfinite(v.x * r) : NEG;
  v.y = (k1 >= cutoff) ? z_dualfinite(v.y * r) : NEG;
  v.z = (k2 >= cutoff) ? z_dualfinite(v.z * r) : NEG;
  v.w = (k3 >= cutoff) ? z_dualfinite(v.w * r) : NEG;
  reinterpret_cast<float4*>(out)[base] = v;
}

extern "C" void kernel_launch(void* const* d_in, const int* in_sizes, int n_in,
                              void* d_out, int out_size, void* d_ws, size_t ws_size,
                              hipStream_t stream) {
  const float* logits = (const float*)d_in[0];
  const float* temps  = (const float*)d_in[1];
  const int*   ks     = (const int*)d_in[2];
  const float* ps     = (const float*)d_in[3];
  float* out = (float*)d_out;

  const int B = in_sizes[1];
  const int V = in_sizes[0] / B;
  const int V4 = V >> 2;

  // d_ws: cntp[B] u32 | flagp[B] u32 | cutp[B] u64 | gcand[B*ZBUF] u64
  unsigned* cntp = (unsigned*)d_ws;
  unsigned* flagp = cntp + B;
  unsigned long long* cutp = (unsigned long long*)(flagp + B);
  unsigned long long* gcand = cutp + B;

  z_init<<<(B + 255) / 256, 256, 0, stream>>>(cntp, flagp, B);
  dim3 gg((V4 + ZTPB - 1) / ZTPB, B);
  z_gather<<<gg, ZTPB, 0, stream>>>(logits, cntp, flagp, gcand, V4);
  z_finish<<<B, ZF_TPB, 0, stream>>>(gcand, cntp, flagp, temps, ks, ps, cutp, V);
  z_fallback<<<B, ZF_TPB, 0, stream>>>(logits, flagp, temps, ks, ps, cutp, V);
  dim3 ga((V4 + 255) / 256, B);
  z_apply<<<ga, 256, 0, stream>>>(logits, temps, cutp, out, V4);
}

// Round 12
// 143.423 us; speedup vs baseline: 16.3386x; 16.3386x over previous
//
#include <hip/hip_runtime.h>
#include <math.h>
#include <float.h>

#define WTPB 1024
#define WSB 16        // gather blocks per row
#define WBUF 4096     // max candidates per row (and per-block staging)
#define WNB 4096
#define WCPAD 32      // counter stride in u32 (128 B -> one cache line/row)
#define T0KEY 0xC0000000u  // f2key(+2.0f): speculative raw-logit threshold

__device__ __forceinline__ unsigned w_f2key(float f) {
  unsigned u = __float_as_uint(f);
  return (u & 0x80000000u) ? ~u : (u | 0x80000000u);
}
__device__ __forceinline__ float w_key2f(unsigned k) {
  unsigned u = (k & 0x80000000u) ? (k & 0x7FFFFFFFu) : ~k;
  return __uint_as_float(u);
}
// Finite as fp32 AND as both bf16 halves (harness reads output as bf16).
__device__ __forceinline__ float w_dualfinite(float x) {
  unsigned u = __float_as_uint(x);
  if ((u & 0x7F800000u) == 0x7F800000u) u = 0xFF7F0000u;
  return __uint_as_float(u & 0xFFFF0000u);
}

// Shared tail: bitonic sort (wave-coherent low strides), softmax cumsum,
// exact top-k tie boundary, top-p crossing -> cutoff.
__device__ void w_tail(unsigned long long* buf, float* csum, float* wsum,
                       int* s_j0, int* s_c, int n, int k, float r, float p,
                       unsigned long long* cut_out, int tid) {
  const int lane = tid & 63;
  const int wave = tid >> 6;
  int m = 64;
  while (m < n) m <<= 1;
  for (int i = n + tid; i < m; i += WTPB) buf[i] = 0xFFFFFFFFFFFFFFFFull;
  __syncthreads();
  for (int size = 2; size <= m; size <<= 1) {
    for (int stride = size >> 1; stride > 0; stride >>= 1) {
      if (stride >= 32) __syncthreads();
      else __asm__ volatile("" ::: "memory");
      for (int i = tid; i < m; i += WTPB) {
        int j = i ^ stride;
        if (j > i) {
          unsigned long long a = buf[i], bb = buf[j];
          bool up = ((i & size) == 0);
          if (up ? (a > bb) : (a < bb)) { buf[i] = bb; buf[j] = a; }
        }
      }
    }
  }
  __syncthreads();

  const float maxv = w_key2f((unsigned)(buf[n - 1] >> 32)) * r;
  const int i0 = tid << 2;
  float e0 = 0.f, e1 = 0.f, e2 = 0.f, e3 = 0.f;
  if (i0 < n)     e0 = expf(w_key2f((unsigned)(buf[i0] >> 32)) * r - maxv);
  if (i0 + 1 < n) e1 = expf(w_key2f((unsigned)(buf[i0 + 1] >> 32)) * r - maxv);
  if (i0 + 2 < n) e2 = expf(w_key2f((unsigned)(buf[i0 + 2] >> 32)) * r - maxv);
  if (i0 + 3 < n) e3 = expf(w_key2f((unsigned)(buf[i0 + 3] >> 32)) * r - maxv);
  const float lsum = e0 + e1 + e2 + e3;
  float vincl = lsum;
  for (int d = 1; d < 64; d <<= 1) {
    float o = __shfl_up(vincl, d);
    if (lane >= d) vincl += o;
  }
  if (lane == 63) wsum[wave] = vincl;
  __syncthreads();
  if (wave == 0 && lane < 16) {
    float s = wsum[lane];
    for (int d = 1; d < 16; d <<= 1) {
      float o = __shfl_up(s, d);
      if (lane >= d) s += o;
    }
    wsum[lane] = s;
  }
  __syncthreads();
  {
    float rr = (wave > 0 ? wsum[wave - 1] : 0.0f) + (vincl - lsum);
    rr += e0; if (i0 < n)     csum[i0] = rr;
    rr += e1; if (i0 + 1 < n) csum[i0 + 1] = rr;
    rr += e2; if (i0 + 2 < n) csum[i0 + 2] = rr;
    rr += e3; if (i0 + 3 < n) csum[i0 + 3] = rr;
  }
  __syncthreads();

  const int k_eff = (k < n) ? k : n;
  const unsigned vkey = (unsigned)(buf[n - k_eff] >> 32);
  if (tid == 0) { *s_j0 = 0; *s_c = n - 1; }
  __syncthreads();
  for (int i = tid; i < n; i += WTPB) {
    unsigned ki = (unsigned)(buf[i] >> 32);
    if (ki == vkey && (i == 0 || (unsigned)(buf[i - 1] >> 32) != vkey))
      *s_j0 = i;
  }
  __syncthreads();
  const int j0 = *s_j0;
  const float base = (j0 > 0) ? csum[j0 - 1] : 0.0f;
  const float Z = csum[n - 1] - base;
  const float thr = (1.0f - p) * Z;
  for (int i = j0 + tid; i < n; i += WTPB) {
    if (csum[i] - base > thr) atomicMin(s_c, i);
  }
  __syncthreads();
  if (tid == 0) *cut_out = buf[*s_c];
}

// K0: zero padded per-row counters and flags.
__global__ void w_init(unsigned* __restrict__ cntp, unsigned* __restrict__ flagp,
                       int B) {
  int i = blockIdx.x * blockDim.x + threadIdx.x;
  if (i < B * WCPAD) cntp[i] = 0u;
  if (i < B) flagp[i] = 0u;
}

// K1: streaming speculative compaction, block-aggregated.
// LDS staging via LDS atomics; ONE global atomicAdd per block to a padded
// per-row counter; coalesced staged->global copy. No cross-XCD line ping-pong.
__global__ __launch_bounds__(WTPB) void w_gather(
    const float* __restrict__ logits, unsigned* __restrict__ cntp,
    unsigned* __restrict__ flagp, unsigned long long* __restrict__ gcand,
    int V4) {
  __shared__ unsigned long long cbuf[WBUF];
  __shared__ unsigned ccnt;
  __shared__ unsigned cbase;
  const int row = blockIdx.y;
  const int tid = threadIdx.x;
  if (tid == 0) ccnt = 0u;
  __syncthreads();
  const int per = (V4 + WSB - 1) / WSB;
  const int lo = blockIdx.x * per;
  int hi = lo + per;
  if (hi > V4) hi = V4;
  const float4* l4 =
      reinterpret_cast<const float4*>(logits) + (size_t)row * V4;
  for (int i = lo + tid; i < hi; i += WTPB) {
    float4 v = l4[i];
    const unsigned basei = (unsigned)(i << 2);
    unsigned key;
    key = w_f2key(v.x);
    if (key >= T0KEY) {
      unsigned pos = atomicAdd(&ccnt, 1u);
      if (pos < WBUF) cbuf[pos] = ((unsigned long long)key << 32) | basei;
    }
    key = w_f2key(v.y);
    if (key >= T0KEY) {
      unsigned pos = atomicAdd(&ccnt, 1u);
      if (pos < WBUF) cbuf[pos] = ((unsigned long long)key << 32) | (basei + 1u);
    }
    key = w_f2key(v.z);
    if (key >= T0KEY) {
      unsigned pos = atomicAdd(&ccnt, 1u);
      if (pos < WBUF) cbuf[pos] = ((unsigned long long)key << 32) | (basei + 2u);
    }
    key = w_f2key(v.w);
    if (key >= T0KEY) {
      unsigned pos = atomicAdd(&ccnt, 1u);
      if (pos < WBUF) cbuf[pos] = ((unsigned long long)key << 32) | (basei + 3u);
    }
  }
  __syncthreads();
  unsigned cn = ccnt;
  if (cn > WBUF) {
    if (tid == 0) atomicOr(&flagp[row], 1u);
    cn = WBUF;
  }
  if (tid == 0) cbase = atomicAdd(&cntp[row * WCPAD], cn);
  __syncthreads();
  const unsigned base = cbase;
  if (tid == 0 && base + cn > WBUF) atomicOr(&flagp[row], 1u);
  unsigned long long* gc = gcand + (size_t)row * WBUF;
  for (unsigned j = tid; j < cn; j += WTPB) {
    unsigned pos = base + j;
    if (pos < WBUF) gc[pos] = cbuf[j];
  }
}

// K2: per-row finish on the speculative candidate set (n >= k guarantees the
// exact top-k is inside it). Flags rows needing the exact fallback.
__global__ __launch_bounds__(WTPB) void w_finish(
    const unsigned long long* __restrict__ gcand,
    const unsigned* __restrict__ cntp, unsigned* __restrict__ flagp,
    const float* __restrict__ temps, const int* __restrict__ ks,
    const float* __restrict__ ps, unsigned long long* __restrict__ cutp,
    int V) {
  __shared__ unsigned long long buf[WBUF];
  __shared__ float csum[WBUF];
  __shared__ float wsum[16];
  __shared__ int s_j0, s_c;
  const int row = blockIdx.x;
  const int tid = threadIdx.x;
  int k = ks[row];
  if (k < 1) k = 1;
  if (k > V) k = V;
  const unsigned n_raw = cntp[row * WCPAD];
  if (flagp[row] != 0u || n_raw > WBUF || (int)n_raw < k) {
    if (tid == 0) flagp[row] = 1u;
    return;
  }
  const int n = (int)n_raw;
  const unsigned long long* gc = gcand + (size_t)row * WBUF;
  for (int i = tid; i < n; i += WTPB) buf[i] = gc[i];
  w_tail(buf, csum, wsum, &s_j0, &s_c, n, k, 1.0f / temps[row], ps[row],
         &cutp[row], tid);
}

// K3: exact multi-level radix-select fallback; only for flagged rows
// (never on this distribution; correctness for arbitrary inputs).
__global__ __launch_bounds__(WTPB) void w_fallback(
    const float* __restrict__ logits, const unsigned* __restrict__ flagp,
    const float* __restrict__ temps, const int* __restrict__ ks,
    const float* __restrict__ ps, unsigned long long* __restrict__ cutp,
    int V) {
  const int row = blockIdx.x;
  if (flagp[row] == 0u) return;
  union U {
    unsigned sel[2 * WNB];
    unsigned long long buf[WBUF];
  };
  __shared__ U sh;
  __shared__ float csum[WBUF];
  __shared__ float wsum[16];
  __shared__ unsigned s_cnt;
  __shared__ unsigned sh_prefix;
  __shared__ int sh_kk;
  __shared__ int s_j0, s_c;
  const int tid = threadIdx.x;
  const float4* l4 =
      reinterpret_cast<const float4*>(logits + (size_t)row * (size_t)V);
  const int V4 = V >> 2;
  int k = ks[row];
  if (k < 1) k = 1;
  if (k > V) k = V;

  // level 0: 12-bit bins; descend only if candidate set would overflow.
  unsigned prefix = 0;
  int kk = k;
  for (int lvl = 0; lvl < 3; ++lvl) {
    const int shift = (lvl == 0) ? 20 : (lvl == 1) ? 8 : 0;
    const int nb = (lvl == 2) ? 256 : 4096;
    for (int i = tid; i < 2 * WNB; i += WTPB) sh.sel[i] = 0;
    __syncthreads();
    if (lvl == 0) {
      for (int i = tid; i < V4; i += WTPB) {
        float4 v = l4[i];
        atomicAdd(&sh.sel[w_f2key(v.x) >> 20], 1u);
        atomicAdd(&sh.sel[w_f2key(v.y) >> 20], 1u);
        atomicAdd(&sh.sel[w_f2key(v.z) >> 20], 1u);
        atomicAdd(&sh.sel[w_f2key(v.w) >> 20], 1u);
      }
    } else {
      const int hs = (lvl == 1) ? 20 : 8;
      const unsigned want = prefix >> hs;
      const unsigned bmask = (unsigned)(nb - 1);
      for (int i = tid; i < V4; i += WTPB) {
        float4 v = l4[i];
        unsigned key;
        key = w_f2key(v.x);
        if ((key >> hs) == want) atomicAdd(&sh.sel[(key >> shift) & bmask], 1u);
        key = w_f2key(v.y);
        if ((key >> hs) == want) atomicAdd(&sh.sel[(key >> shift) & bmask], 1u);
        key = w_f2key(v.z);
        if ((key >> hs) == want) atomicAdd(&sh.sel[(key >> shift) & bmask], 1u);
        key = w_f2key(v.w);
        if ((key >> hs) == want) atomicAdd(&sh.sel[(key >> shift) & bmask], 1u);
      }
    }
    __syncthreads();
    if (tid == 0) {
      int acc = 0;
      sh_prefix = prefix;
      sh_kk = kk;
      for (int b = nb - 1; b >= 0; --b) {
        int h = (int)sh.sel[b];
        if (acc + h >= kk) {
          sh_kk = kk - acc;
          sh_prefix = prefix | ((unsigned)b << shift);
          break;
        }
        acc += h;
      }
    }
    __syncthreads();
    prefix = sh_prefix;
    kk = sh_kk;
    __syncthreads();
    if (lvl == 2) break;
    // count candidates at this threshold; stop if they fit.
    if (tid == 0) s_cnt = 0;
    __syncthreads();
    for (int i = tid; i < V4; i += WTPB) {
      float4 v = l4[i];
      unsigned c = (w_f2key(v.x) >= prefix) + (w_f2key(v.y) >= prefix) +
                   (w_f2key(v.z) >= prefix) + (w_f2key(v.w) >= prefix);
      if (c) atomicAdd(&s_cnt, c);
    }
    __syncthreads();
    if (s_cnt <= (unsigned)WBUF) break;
    __syncthreads();
  }
  const unsigned thr = prefix;

  if (tid == 0) s_cnt = 0;
  __syncthreads();
  for (int i = tid; i < V4; i += WTPB) {
    float4 v = l4[i];
    const unsigned basei = (unsigned)(i << 2);
    unsigned key;
    key = w_f2key(v.x);
    if (key >= thr) {
      unsigned pos = atomicAdd(&s_cnt, 1u);
      if (pos < WBUF) sh.buf[pos] = ((unsigned long long)key << 32) | basei;
    }
    key = w_f2key(v.y);
    if (key >= thr) {
      unsigned pos = atomicAdd(&s_cnt, 1u);
      if (pos < WBUF) sh.buf[pos] = ((unsigned long long)key << 32) | (basei + 1u);
    }
    key = w_f2key(v.z);
    if (key >= thr) {
      unsigned pos = atomicAdd(&s_cnt, 1u);
      if (pos < WBUF) sh.buf[pos] = ((unsigned long long)key << 32) | (basei + 2u);
    }
    key = w_f2key(v.w);
    if (key >= thr) {
      unsigned pos = atomicAdd(&s_cnt, 1u);
      if (pos < WBUF) sh.buf[pos] = ((unsigned long long)key << 32) | (basei + 3u);
    }
  }
  __syncthreads();
  int n = (int)s_cnt;
  if (n > WBUF) n = WBUF;
  if (n < 1) n = 1;
  w_tail(sh.buf, csum, wsum, &s_j0, &s_c, n, k, 1.0f / temps[row], ps[row],
         &cutp[row], tid);
}

// K4: fat apply on raw keys; scale survivors by r = 1/T. Sole writer of
// final d_out; dual-finite everywhere.
__global__ void w_apply(const float* __restrict__ logits,
                        const float* __restrict__ temps,
                        const unsigned long long* __restrict__ cutp,
                        float* __restrict__ out, int V4) {
  const int row = blockIdx.y;
  const int i = blockIdx.x * blockDim.x + threadIdx.x;
  if (i >= V4) return;
  const float r = 1.0f / temps[row];
  const unsigned long long cutoff = cutp[row];
  const size_t base = (size_t)row * (size_t)V4 + i;
  float4 v = reinterpret_cast<const float4*>(logits)[base];
  const float NEG = __uint_as_float(0xFF7F0000u);
  const unsigned e = (unsigned)(i << 2);
  unsigned long long k0 = ((unsigned long long)w_f2key(v.x) << 32) | e;
  unsigned long long k1 = ((unsigned long long)w_f2key(v.y) << 32) | (e + 1u);
  unsigned long long k2 = ((unsigned long long)w_f2key(v.z) << 32) | (e + 2u);
  unsigned long long k3 = ((unsigned long long)w_f2key(v.w) << 32) | (e + 3u);
  v.x = (k0 >= cutoff) ? w_dualfinite(v.x * r) : NEG;
  v.y = (k1 >= cutoff) ? w_dualfinite(v.y * r) : NEG;
  v.z = (k2 >= cutoff) ? w_dualfinite(v.z * r) : NEG;
  v.w = (k3 >= cutoff) ? w_dualfinite(v.w * r) : NEG;
  reinterpret_cast<float4*>(out)[base] = v;
}

extern "C" void kernel_launch(void* const* d_in, const int* in_sizes, int n_in,
                              void* d_out, int out_size, void* d_ws, size_t ws_size,
                              hipStream_t stream) {
  const float* logits = (const float*)d_in[0];
  const float* temps  = (const float*)d_in[1];
  const int*   ks     = (const int*)d_in[2];
  const float* ps     = (const float*)d_in[3];
  float* out = (float*)d_out;

  const int B = in_sizes[1];
  const int V = in_sizes[0] / B;
  const int V4 = V >> 2;

  // d_ws: cntp[B*WCPAD] u32 | flagp[B] u32 | cutp[B] u64 | gcand[B*WBUF] u64
  unsigned* cntp = (unsigned*)d_ws;
  unsigned* flagp = cntp + (size_t)B * WCPAD;
  unsigned long long* cutp = (unsigned long long*)(flagp + B);
  unsigned long long* gcand = cutp + B;

  w_init<<<(B * WCPAD + 1023) / 1024, 1024, 0, stream>>>(cntp, flagp, B);
  dim3 gg(WSB, B);
  w_gather<<<gg, WTPB, 0, stream>>>(logits, cntp, flagp, gcand, V4);
  w_finish<<<B, WTPB, 0, stream>>>(gcand, cntp, flagp, temps, ks, ps, cutp, V);
  w_fallback<<<B, WTPB, 0, stream>>>(logits, flagp, temps, ks, ps, cutp, V);
  dim3 ga((V4 + 255) / 256, B);
  w_apply<<<ga, 256, 0, stream>>>(logits, temps, cutp, out, V4);
}

// Round 13
// 94.411 us; speedup vs baseline: 24.8205x; 1.5191x over previous
//
#include <hip/hip_runtime.h>
#include <math.h>
#include <float.h>

#define WTPB 1024
#define WSB 2         // gather blocks per row
#define WBUF 4096     // max candidates per row
#define WNB 4096
#define WCPAD 32      // counter stride (128B -> one cache line per row)
#define T0KEY 0xC0000000u  // f2key(+2.0f): speculative raw-logit threshold

__device__ __forceinline__ unsigned w_f2key(float f) {
  unsigned u = __float_as_uint(f);
  return (u & 0x80000000u) ? ~u : (u | 0x80000000u);
}
__device__ __forceinline__ float w_key2f(unsigned k) {
  unsigned u = (k & 0x80000000u) ? (k & 0x7FFFFFFFu) : ~k;
  return __uint_as_float(u);
}
// Finite as fp32 AND as both bf16 halves (harness reads output as bf16).
__device__ __forceinline__ float w_dualfinite(float x) {
  unsigned u = __float_as_uint(x);
  if ((u & 0x7F800000u) == 0x7F800000u) u = 0xFF7F0000u;
  return __uint_as_float(u & 0xFFFF0000u);
}
__device__ __forceinline__ unsigned long long w_pfx(unsigned long long v,
                                                    int lane) {
  for (int d = 1; d < 64; d <<= 1) {
    unsigned long long o = __shfl_up(v, d);
    if (lane >= d) v += o;
  }
  return v;
}
__device__ __forceinline__ unsigned long long w_red(unsigned long long v) {
  for (int d = 32; d > 0; d >>= 1) v += __shfl_down(v, d);
  return v;  // lane 0 holds the sum
}
// fixed-point exp (scale 2^30), identical across passes -> deterministic
__device__ __forceinline__ unsigned long long w_efix(unsigned key, float maxv,
                                                     float r) {
  float e = expf((w_key2f(key) - maxv) * r);
  return (unsigned long long)(e * 1073741824.0f);
}

// K0: zero padded per-row counters and flags.
__global__ void w_init(unsigned* __restrict__ cntp, unsigned* __restrict__ flagp,
                       int B) {
  int i = blockIdx.x * blockDim.x + threadIdx.x;
  if (i < B * WCPAD) cntp[i] = 0u;
  if (i < B) flagp[i] = 0u;
}

// K1: streaming speculative compaction, block-aggregated (one global
// atomicAdd per block on a padded per-row counter).
__global__ __launch_bounds__(WTPB) void w_gather(
    const float* __restrict__ logits, unsigned* __restrict__ cntp,
    unsigned* __restrict__ flagp, unsigned long long* __restrict__ gcand,
    int V4) {
  __shared__ unsigned long long cbuf[WBUF];
  __shared__ unsigned ccnt;
  __shared__ unsigned cbase;
  const int row = blockIdx.y;
  const int tid = threadIdx.x;
  if (tid == 0) ccnt = 0u;
  __syncthreads();
  const int per = (V4 + WSB - 1) / WSB;
  const int lo = blockIdx.x * per;
  int hi = lo + per;
  if (hi > V4) hi = V4;
  const float4* l4 = reinterpret_cast<const float4*>(logits) + (size_t)row * V4;
  for (int i = lo + tid; i < hi; i += WTPB) {
    float4 v = l4[i];
    const unsigned basei = (unsigned)(i << 2);
    unsigned key;
    key = w_f2key(v.x);
    if (key >= T0KEY) {
      unsigned pos = atomicAdd(&ccnt, 1u);
      if (pos < WBUF) cbuf[pos] = ((unsigned long long)key << 32) | basei;
    }
    key = w_f2key(v.y);
    if (key >= T0KEY) {
      unsigned pos = atomicAdd(&ccnt, 1u);
      if (pos < WBUF) cbuf[pos] = ((unsigned long long)key << 32) | (basei + 1u);
    }
    key = w_f2key(v.z);
    if (key >= T0KEY) {
      unsigned pos = atomicAdd(&ccnt, 1u);
      if (pos < WBUF) cbuf[pos] = ((unsigned long long)key << 32) | (basei + 2u);
    }
    key = w_f2key(v.w);
    if (key >= T0KEY) {
      unsigned pos = atomicAdd(&ccnt, 1u);
      if (pos < WBUF) cbuf[pos] = ((unsigned long long)key << 32) | (basei + 3u);
    }
  }
  __syncthreads();
  unsigned cn = ccnt;
  if (cn > WBUF) {
    if (tid == 0) atomicOr(&flagp[row], 1u);
    cn = WBUF;
  }
  if (tid == 0) cbase = atomicAdd(&cntp[row * WCPAD], cn);
  __syncthreads();
  const unsigned base = cbase;
  if (tid == 0 && base + cn > WBUF) atomicOr(&flagp[row], 1u);
  unsigned long long* gc = gcand + (size_t)row * WBUF;
  for (unsigned j = tid; j < cn; j += WTPB) {
    unsigned pos = base + j;
    if (pos < WBUF) gc[pos] = cbuf[j];
  }
}

// K2: sort-free per-row tail. Multi-level (12/10/10-bit) histogram descends:
// vkey by count-rank; top-p crossing by fixed-point exp-sum prefix. All
// integer accumulation (deterministic, order-free wrt compaction order).
__global__ __launch_bounds__(WTPB) void w_finish2(
    const unsigned long long* __restrict__ gcand,
    const unsigned* __restrict__ cntp, unsigned* __restrict__ flagp,
    const float* __restrict__ temps, const int* __restrict__ ks,
    const float* __restrict__ ps, unsigned long long* __restrict__ cutp,
    int V) {
  __shared__ unsigned long long H[WNB];   // 32 KB: L0 hist (cnt then sum)
  __shared__ unsigned long long H1[1024]; // 8 KB: L1/L2 hists
  __shared__ unsigned long long G[64];    // group partials
  __shared__ unsigned tieidx[256];
  __shared__ struct {
    unsigned flag, maxkey, b0, b1, vkey, b0c, b1c, kc, tcnt, cutidx, mreq;
    int selg;
    unsigned long long rank, resid, base, tot, T;
  } sc;

  const int row = blockIdx.x;
  const int tid = threadIdx.x;
  const int lane = tid & 63;
  const int wv = tid >> 6;
  int k = ks[row];
  if (k < 1) k = 1;
  if (k > V) k = V;
  const float p = ps[row];
  const float r = 1.0f / temps[row];
  const unsigned n_raw = cntp[row * WCPAD];
  if (flagp[row] != 0u || n_raw > WBUF || (int)n_raw < k) {
    if (tid == 0) flagp[row] = 1u;
    return;
  }
  const int n = (int)n_raw;
  const unsigned long long* gc = gcand + (size_t)row * WBUF;

  if (tid == 0) sc.flag = 0u;
  // ---- pass A: L0 count hist + row max key ----
  for (int i = tid; i < WNB; i += WTPB) H[i] = 0ull;
  __syncthreads();
  unsigned mk = 0u;
  for (int i = tid; i < n; i += WTPB) {
    unsigned key = (unsigned)(gc[i] >> 32);
    atomicAdd(&H[key >> 20], 1ull);
    if (key > mk) mk = key;
  }
  {  // max reduce
    unsigned long long v = mk;
    v = w_red(v);  // within-wave max? no—w_red sums. do max manually:
  }
  // wave max via shuffles
  for (int d = 32; d > 0; d >>= 1) {
    unsigned o = __shfl_down(mk, d);
    if (o > mk) mk = o;
  }
  if (lane == 0) G[wv] = mk;
  __syncthreads();
  if (wv == 0) {
    unsigned m2 = (lane < 16) ? (unsigned)G[lane] : 0u;
    for (int d = 32; d > 0; d >>= 1) {
      unsigned o = __shfl_down(m2, d);
      if (o > m2) m2 = o;
    }
    if (lane == 0) sc.maxkey = m2;
  }
  __syncthreads();
  const float maxv = w_key2f(sc.maxkey);

  // ---- L0 cnt descend (suffix, rank k) ----
  for (int q = 0; q < 4; ++q) {
    int g = wv * 4 + q;
    unsigned long long s = w_red(H[g * 64 + lane]);
    if (lane == 0) G[g] = s;
  }
  __syncthreads();
  if (wv == 0) {
    unsigned long long pf = w_pfx(G[63 - lane], lane);
    int L = __ffsll(__ballot(pf >= (unsigned long long)k)) - 1;
    unsigned long long above = (L > 0) ? __shfl(pf, L - 1) : 0ull;
    if (lane == 0) { sc.selg = 63 - L; sc.rank = (unsigned long long)k - above; }
  }
  __syncthreads();
  if (wv == 0) {
    int g = sc.selg;
    unsigned long long pf = w_pfx(H[g * 64 + (63 - lane)], lane);
    int L = __ffsll(__ballot(pf >= sc.rank)) - 1;
    unsigned long long above = (L > 0) ? __shfl(pf, L - 1) : 0ull;
    if (lane == 0) { sc.b0 = g * 64 + (63 - L); sc.rank = sc.rank - above; }
  }
  __syncthreads();
  // ---- L1 cnt ----
  for (int i = tid; i < 1024; i += WTPB) H1[i] = 0ull;
  __syncthreads();
  {
    const unsigned b0 = sc.b0;
    for (int i = tid; i < n; i += WTPB) {
      unsigned key = (unsigned)(gc[i] >> 32);
      if ((key >> 20) == b0) atomicAdd(&H1[(key >> 10) & 1023u], 1ull);
    }
  }
  __syncthreads();
  {
    unsigned long long s = w_red(H1[wv * 64 + lane]);
    if (lane == 0) G[wv] = s;
  }
  __syncthreads();
  if (wv == 0) {
    unsigned long long gv = (lane < 16) ? G[15 - lane] : 0ull;
    unsigned long long pf = w_pfx(gv, lane);
    int L = __ffsll(__ballot((lane < 16) && (pf >= sc.rank))) - 1;
    unsigned long long above = (L > 0) ? __shfl(pf, L - 1) : 0ull;
    if (lane == 0) { sc.selg = 15 - L; sc.rank = sc.rank - above; }
  }
  __syncthreads();
  if (wv == 0) {
    int g = sc.selg;
    unsigned long long pf = w_pfx(H1[g * 64 + (63 - lane)], lane);
    int L = __ffsll(__ballot(pf >= sc.rank)) - 1;
    unsigned long long above = (L > 0) ? __shfl(pf, L - 1) : 0ull;
    if (lane == 0) { sc.b1 = g * 64 + (63 - L); sc.rank = sc.rank - above; }
  }
  __syncthreads();
  // ---- L2 cnt ----
  for (int i = tid; i < 1024; i += WTPB) H1[i] = 0ull;
  __syncthreads();
  {
    const unsigned pref = (sc.b0 << 10) | sc.b1;
    for (int i = tid; i < n; i += WTPB) {
      unsigned key = (unsigned)(gc[i] >> 32);
      if ((key >> 10) == pref) atomicAdd(&H1[key & 1023u], 1ull);
    }
  }
  __syncthreads();
  {
    unsigned long long s = w_red(H1[wv * 64 + lane]);
    if (lane == 0) G[wv] = s;
  }
  __syncthreads();
  if (wv == 0) {
    unsigned long long gv = (lane < 16) ? G[15 - lane] : 0ull;
    unsigned long long pf = w_pfx(gv, lane);
    int L = __ffsll(__ballot((lane < 16) && (pf >= sc.rank))) - 1;
    unsigned long long above = (L > 0) ? __shfl(pf, L - 1) : 0ull;
    if (lane == 0) { sc.selg = 15 - L; sc.rank = sc.rank - above; }
  }
  __syncthreads();
  if (wv == 0) {
    int g = sc.selg;
    unsigned long long pf = w_pfx(H1[g * 64 + (63 - lane)], lane);
    int L = __ffsll(__ballot(pf >= sc.rank)) - 1;
    if (lane == 0) sc.vkey = (sc.b0 << 20) | (sc.b1 << 10) | (g * 64 + (63 - L));
  }
  __syncthreads();
  const unsigned vkey = sc.vkey;

  // ---- base (sum e for key < vkey) and total ----
  {
    unsigned long long tb = 0ull, tt = 0ull;
    for (int i = tid; i < n; i += WTPB) {
      unsigned key = (unsigned)(gc[i] >> 32);
      unsigned long long e = w_efix(key, maxv, r);
      tt += e;
      if (key < vkey) tb += e;
    }
    tt = w_red(tt);
    tb = w_red(tb);
    if (lane == 0) { G[wv] = tt; G[16 + wv] = tb; }
  }
  __syncthreads();
  if (wv == 0) {
    unsigned long long tt = w_red((lane < 16) ? G[lane] : 0ull);
    unsigned long long tb = w_red((lane < 16) ? G[16 + lane] : 0ull);
    if (lane == 0) {
      sc.tot = tt;
      sc.base = tb;
      unsigned long long Z = tt - tb;
      if (Z == 0ull) sc.flag = 1u;
      else {
        unsigned long long T = tb + (unsigned long long)((double)(1.0f - p) * (double)Z);
        if (T >= tt) sc.flag = 1u;
        sc.T = T;
      }
    }
  }
  __syncthreads();
  if (sc.flag) { if (tid == 0) flagp[row] = 1u; return; }
  // ---- L0 sum descend (ascending prefix vs T) ----
  for (int i = tid; i < WNB; i += WTPB) H[i] = 0ull;
  __syncthreads();
  for (int i = tid; i < n; i += WTPB) {
    unsigned key = (unsigned)(gc[i] >> 32);
    atomicAdd(&H[key >> 20], w_efix(key, maxv, r));
  }
  __syncthreads();
  for (int q = 0; q < 4; ++q) {
    int g = wv * 4 + q;
    unsigned long long s = w_red(H[g * 64 + lane]);
    if (lane == 0) G[g] = s;
  }
  __syncthreads();
  if (wv == 0) {
    unsigned long long pf = w_pfx(G[lane], lane);
    int L = __ffsll(__ballot(pf > sc.T)) - 1;
    unsigned long long excl = (L > 0) ? __shfl(pf, L - 1) : 0ull;
    if (lane == 0) { sc.selg = L; sc.resid = sc.T - excl; }
  }
  __syncthreads();
  if (wv == 0) {
    int g = sc.selg;
    unsigned long long pf = w_pfx(H[g * 64 + lane], lane);
    int L = __ffsll(__ballot(pf > sc.resid)) - 1;
    unsigned long long excl = (L > 0) ? __shfl(pf, L - 1) : 0ull;
    if (lane == 0) { sc.b0c = g * 64 + L; sc.resid = sc.resid - excl; }
  }
  __syncthreads();
  // ---- L1 sum ----
  for (int i = tid; i < 1024; i += WTPB) H1[i] = 0ull;
  __syncthreads();
  {
    const unsigned b0 = sc.b0c;
    for (int i = tid; i < n; i += WTPB) {
      unsigned key = (unsigned)(gc[i] >> 32);
      if ((key >> 20) == b0) atomicAdd(&H1[(key >> 10) & 1023u], w_efix(key, maxv, r));
    }
  }
  __syncthreads();
  {
    unsigned long long s = w_red(H1[wv * 64 + lane]);
    if (lane == 0) G[wv] = s;
  }
  __syncthreads();
  if (wv == 0) {
    unsigned long long gv = (lane < 16) ? G[lane] : 0ull;
    unsigned long long pf = w_pfx(gv, lane);
    int L = __ffsll(__ballot((lane < 16) && (pf > sc.resid))) - 1;
    unsigned long long excl = (L > 0) ? __shfl(pf, L - 1) : 0ull;
    if (lane == 0) { sc.selg = L; sc.resid = sc.resid - excl; }
  }
  __syncthreads();
  if (wv == 0) {
    int g = sc.selg;
    unsigned long long pf = w_pfx(H1[g * 64 + lane], lane);
    int L = __ffsll(__ballot(pf > sc.resid)) - 1;
    unsigned long long excl = (L > 0) ? __shfl(pf, L - 1) : 0ull;
    if (lane == 0) { sc.b1c = g * 64 + L; sc.resid = sc.resid - excl; }
  }
  __syncthreads();
  // ---- L2 sum -> exact crossing key ----
  for (int i = tid; i < 1024; i += WTPB) H1[i] = 0ull;
  __syncthreads();
  {
    const unsigned pref = (sc.b0c << 10) | sc.b1c;
    for (int i = tid; i < n; i += WTPB) {
      unsigned key = (unsigned)(gc[i] >> 32);
      if ((key >> 10) == pref) atomicAdd(&H1[key & 1023u], w_efix(key, maxv, r));
    }
  }
  __syncthreads();
  {
    unsigned long long s = w_red(H1[wv * 64 + lane]);
    if (lane == 0) G[wv] = s;
  }
  __syncthreads();
  if (wv == 0) {
    unsigned long long gv = (lane < 16) ? G[lane] : 0ull;
    unsigned long long pf = w_pfx(gv, lane);
    int L = __ffsll(__ballot((lane < 16) && (pf > sc.resid))) - 1;
    unsigned long long excl = (L > 0) ? __shfl(pf, L - 1) : 0ull;
    if (lane == 0) { sc.selg = L; sc.resid = sc.resid - excl; }
  }
  __syncthreads();
  if (wv == 0) {
    int g = sc.selg;
    unsigned long long pf = w_pfx(H1[g * 64 + lane], lane);
    int L = __ffsll(__ballot(pf > sc.resid)) - 1;
    unsigned long long excl = (L > 0) ? __shfl(pf, L - 1) : 0ull;
    if (lane == 0) {
      sc.kc = (sc.b0c << 20) | (sc.b1c << 10) | (unsigned)(g * 64 + L);
      sc.resid = sc.resid - excl;
    }
  }
  __syncthreads();
  const unsigned kc = sc.kc;
  {
    unsigned long long ek = w_efix(kc, maxv, r);
    if (tid == 0) {
      if (ek == 0ull) sc.flag = 1u;
      else sc.mreq = (unsigned)(sc.resid / ek + 1ull);
      sc.tcnt = 0u;
    }
  }
  __syncthreads();
  if (sc.flag) { if (tid == 0) flagp[row] = 1u; return; }
  // ---- gather tie group (key == kc), select mreq-th smallest idx ----
  for (int i = tid; i < n; i += WTPB) {
    unsigned long long e = gc[i];
    if ((unsigned)(e >> 32) == kc) {
      unsigned pos = atomicAdd(&sc.tcnt, 1u);
      if (pos < 256u) tieidx[pos] = (unsigned)(e & 0xFFFFFFFFu);
    }
  }
  __syncthreads();
  const unsigned t = sc.tcnt;
  if (t > 256u || sc.mreq > t) {
    if (tid == 0) flagp[row] = 1u;
    return;
  }
  if (tid < (int)t) {
    unsigned my = tieidx[tid];
    unsigned rank = 0;
    for (unsigned j = 0; j < t; ++j) rank += (tieidx[j] < my) ? 1u : 0u;
    if (rank == sc.mreq - 1u) sc.cutidx = my;
  }
  __syncthreads();
  if (tid == 0) cutp[row] = ((unsigned long long)kc << 32) | sc.cutidx;
}

// K3: exact fallback (flagged rows only): full radix select + bitonic tail.
__global__ __launch_bounds__(WTPB) void w_fallback(
    const float* __restrict__ logits, const unsigned* __restrict__ flagp,
    const float* __restrict__ temps, const int* __restrict__ ks,
    const float* __restrict__ ps, unsigned long long* __restrict__ cutp,
    int V) {
  const int row = blockIdx.x;
  if (flagp[row] == 0u) return;
  union U {
    unsigned sel[2 * WNB];
    unsigned long long buf[WBUF];
  };
  __shared__ U sh;
  __shared__ float csum[WBUF];
  __shared__ float wsum[16];
  __shared__ unsigned s_cnt;
  __shared__ unsigned sh_prefix;
  __shared__ int sh_kk;
  __shared__ int s_j0, s_c;
  const int tid = threadIdx.x;
  const int lane = tid & 63;
  const int wave = tid >> 6;
  const float4* l4 =
      reinterpret_cast<const float4*>(logits + (size_t)row * (size_t)V);
  const int V4 = V >> 2;
  int k = ks[row];
  if (k < 1) k = 1;
  if (k > V) k = V;
  const float p = ps[row];
  const float r = 1.0f / temps[row];

  unsigned prefix = 0;
  int kk = k;
  for (int lvl = 0; lvl < 3; ++lvl) {
    const int shift = (lvl == 0) ? 20 : (lvl == 1) ? 8 : 0;
    const int nb = (lvl == 2) ? 256 : 4096;
    for (int i = tid; i < 2 * WNB; i += WTPB) sh.sel[i] = 0;
    __syncthreads();
    if (lvl == 0) {
      for (int i = tid; i < V4; i += WTPB) {
        float4 v = l4[i];
        atomicAdd(&sh.sel[w_f2key(v.x) >> 20], 1u);
        atomicAdd(&sh.sel[w_f2key(v.y) >> 20], 1u);
        atomicAdd(&sh.sel[w_f2key(v.z) >> 20], 1u);
        atomicAdd(&sh.sel[w_f2key(v.w) >> 20], 1u);
      }
    } else {
      const int hs = (lvl == 1) ? 20 : 8;
      const unsigned want = prefix >> hs;
      const unsigned bmask = (unsigned)(nb - 1);
      for (int i = tid; i < V4; i += WTPB) {
        float4 v = l4[i];
        unsigned key;
        key = w_f2key(v.x);
        if ((key >> hs) == want) atomicAdd(&sh.sel[(key >> shift) & bmask], 1u);
        key = w_f2key(v.y);
        if ((key >> hs) == want) atomicAdd(&sh.sel[(key >> shift) & bmask], 1u);
        key = w_f2key(v.z);
        if ((key >> hs) == want) atomicAdd(&sh.sel[(key >> shift) & bmask], 1u);
        key = w_f2key(v.w);
        if ((key >> hs) == want) atomicAdd(&sh.sel[(key >> shift) & bmask], 1u);
      }
    }
    __syncthreads();
    if (tid == 0) {
      int acc = 0;
      sh_prefix = prefix;
      sh_kk = kk;
      for (int b = nb - 1; b >= 0; --b) {
        int h = (int)sh.sel[b];
        if (acc + h >= kk) {
          sh_kk = kk - acc;
          sh_prefix = prefix | ((unsigned)b << shift);
          break;
        }
        acc += h;
      }
    }
    __syncthreads();
    prefix = sh_prefix;
    kk = sh_kk;
    __syncthreads();
    if (lvl == 2) break;
    if (tid == 0) s_cnt = 0;
    __syncthreads();
    for (int i = tid; i < V4; i += WTPB) {
      float4 v = l4[i];
      unsigned c = (w_f2key(v.x) >= prefix) + (w_f2key(v.y) >= prefix) +
                   (w_f2key(v.z) >= prefix) + (w_f2key(v.w) >= prefix);
      if (c) atomicAdd(&s_cnt, c);
    }
    __syncthreads();
    if (s_cnt <= (unsigned)WBUF) break;
    __syncthreads();
  }
  const unsigned thr = prefix;

  if (tid == 0) s_cnt = 0;
  __syncthreads();
  for (int i = tid; i < V4; i += WTPB) {
    float4 v = l4[i];
    const unsigned basei = (unsigned)(i << 2);
    unsigned key;
    key = w_f2key(v.x);
    if (key >= thr) {
      unsigned pos = atomicAdd(&s_cnt, 1u);
      if (pos < WBUF) sh.buf[pos] = ((unsigned long long)key << 32) | basei;
    }
    key = w_f2key(v.y);
    if (key >= thr) {
      unsigned pos = atomicAdd(&s_cnt, 1u);
      if (pos < WBUF) sh.buf[pos] = ((unsigned long long)key << 32) | (basei + 1u);
    }
    key = w_f2key(v.z);
    if (key >= thr) {
      unsigned pos = atomicAdd(&s_cnt, 1u);
      if (pos < WBUF) sh.buf[pos] = ((unsigned long long)key << 32) | (basei + 2u);
    }
    key = w_f2key(v.w);
    if (key >= thr) {
      unsigned pos = atomicAdd(&s_cnt, 1u);
      if (pos < WBUF) sh.buf[pos] = ((unsigned long long)key << 32) | (basei + 3u);
    }
  }
  __syncthreads();
  int n = (int)s_cnt;
  if (n > WBUF) n = WBUF;
  if (n < 1) n = 1;

  int m = 64;
  while (m < n) m <<= 1;
  for (int i = n + tid; i < m; i += WTPB) sh.buf[i] = 0xFFFFFFFFFFFFFFFFull;
  __syncthreads();
  for (int size = 2; size <= m; size <<= 1) {
    for (int stride = size >> 1; stride > 0; stride >>= 1) {
      if (stride >= 32) __syncthreads();
      else __asm__ volatile("" ::: "memory");
      for (int i = tid; i < m; i += WTPB) {
        int j = i ^ stride;
        if (j > i) {
          unsigned long long a = sh.buf[i], bb = sh.buf[j];
          bool up = ((i & size) == 0);
          if (up ? (a > bb) : (a < bb)) { sh.buf[i] = bb; sh.buf[j] = a; }
        }
      }
    }
  }
  __syncthreads();

  const float maxv = w_key2f((unsigned)(sh.buf[n - 1] >> 32)) * r;
  const int i0 = tid << 2;
  float e0 = 0.f, e1 = 0.f, e2 = 0.f, e3 = 0.f;
  if (i0 < n)     e0 = expf(w_key2f((unsigned)(sh.buf[i0] >> 32)) * r - maxv);
  if (i0 + 1 < n) e1 = expf(w_key2f((unsigned)(sh.buf[i0 + 1] >> 32)) * r - maxv);
  if (i0 + 2 < n) e2 = expf(w_key2f((unsigned)(sh.buf[i0 + 2] >> 32)) * r - maxv);
  if (i0 + 3 < n) e3 = expf(w_key2f((unsigned)(sh.buf[i0 + 3] >> 32)) * r - maxv);
  const float lsum = e0 + e1 + e2 + e3;
  float vincl = lsum;
  for (int d = 1; d < 64; d <<= 1) {
    float o = __shfl_up(vincl, d);
    if (lane >= d) vincl += o;
  }
  if (lane == 63) wsum[wave] = vincl;
  __syncthreads();
  if (wave == 0 && lane < 16) {
    float s = wsum[lane];
    for (int d = 1; d < 16; d <<= 1) {
      float o = __shfl_up(s, d);
      if (lane >= d) s += o;
    }
    wsum[lane] = s;
  }
  __syncthreads();
  {
    float rr = (wave > 0 ? wsum[wave - 1] : 0.0f) + (vincl - lsum);
    rr += e0; if (i0 < n)     csum[i0] = rr;
    rr += e1; if (i0 + 1 < n) csum[i0 + 1] = rr;
    rr += e2; if (i0 + 2 < n) csum[i0 + 2] = rr;
    rr += e3; if (i0 + 3 < n) csum[i0 + 3] = rr;
  }
  __syncthreads();

  const int k_eff = (k < n) ? k : n;
  const unsigned vkey = (unsigned)(sh.buf[n - k_eff] >> 32);
  if (tid == 0) { s_j0 = 0; s_c = n - 1; }
  __syncthreads();
  for (int i = tid; i < n; i += WTPB) {
    unsigned ki = (unsigned)(sh.buf[i] >> 32);
    if (ki == vkey && (i == 0 || (unsigned)(sh.buf[i - 1] >> 32) != vkey))
      s_j0 = i;
  }
  __syncthreads();
  const int j0 = s_j0;
  const float base = (j0 > 0) ? csum[j0 - 1] : 0.0f;
  const float Z = csum[n - 1] - base;
  const float thrp = (1.0f - p) * Z;
  for (int i = j0 + tid; i < n; i += WTPB) {
    if (csum[i] - base > thrp) atomicMin(&s_c, i);
  }
  __syncthreads();
  if (tid == 0) cutp[row] = sh.buf[s_c];
}

// K4: fat apply; sole writer of final d_out; dual-finite everywhere.
__global__ void w_apply(const float* __restrict__ logits,
                        const float* __restrict__ temps,
                        const unsigned long long* __restrict__ cutp,
                        float* __restrict__ out, int V4) {
  const int row = blockIdx.y;
  const int i = blockIdx.x * blockDim.x + threadIdx.x;
  if (i >= V4) return;
  const float r = 1.0f / temps[row];
  const unsigned long long cutoff = cutp[row];
  const size_t base = (size_t)row * (size_t)V4 + i;
  float4 v = reinterpret_cast<const float4*>(logits)[base];
  const float NEG = __uint_as_float(0xFF7F0000u);
  const unsigned e = (unsigned)(i << 2);
  unsigned long long k0 = ((unsigned long long)w_f2key(v.x) << 32) | e;
  unsigned long long k1 = ((unsigned long long)w_f2key(v.y) << 32) | (e + 1u);
  unsigned long long k2 = ((unsigned long long)w_f2key(v.z) << 32) | (e + 2u);
  unsigned long long k3 = ((unsigned long long)w_f2key(v.w) << 32) | (e + 3u);
  v.x = (k0 >= cutoff) ? w_dualfinite(v.x * r) : NEG;
  v.y = (k1 >= cutoff) ? w_dualfinite(v.y * r) : NEG;
  v.z = (k2 >= cutoff) ? w_dualfinite(v.z * r) : NEG;
  v.w = (k3 >= cutoff) ? w_dualfinite(v.w * r) : NEG;
  reinterpret_cast<float4*>(out)[base] = v;
}

extern "C" void kernel_launch(void* const* d_in, const int* in_sizes, int n_in,
                              void* d_out, int out_size, void* d_ws, size_t ws_size,
                              hipStream_t stream) {
  const float* logits = (const float*)d_in[0];
  const float* temps  = (const float*)d_in[1];
  const int*   ks     = (const int*)d_in[2];
  const float* ps     = (const float*)d_in[3];
  float* out = (float*)d_out;

  const int B = in_sizes[1];
  const int V = in_sizes[0] / B;
  const int V4 = V >> 2;

  unsigned* cntp = (unsigned*)d_ws;
  unsigned* flagp = cntp + (size_t)B * WCPAD;
  unsigned long long* cutp = (unsigned long long*)(flagp + B);
  unsigned long long* gcand = cutp + B;

  w_init<<<(B * WCPAD + 1023) / 1024, 1024, 0, stream>>>(cntp, flagp, B);
  dim3 gg(WSB, B);
  w_gather<<<gg, WTPB, 0, stream>>>(logits, cntp, flagp, gcand, V4);
  w_finish2<<<B, WTPB, 0, stream>>>(gcand, cntp, flagp, temps, ks, ps, cutp, V);
  w_fallback<<<B, WTPB, 0, stream>>>(logits, flagp, temps, ks, ps, cutp, V);
  dim3 ga((V4 + 255) / 256, B);
  w_apply<<<ga, 256, 0, stream>>>(logits, temps, cutp, out, V4);
}

// Round 14
// 87.931 us; speedup vs baseline: 26.6496x; 1.0737x over previous
//
#include <hip/hip_runtime.h>
#include <math.h>
#include <float.h>

#define GTPB 512      // gather block size
#define FTPB 1024     // finish block size
#define WSB 4         // gather blocks per row
#define WSEG 1024     // per-block candidate segment
#define WBUF 4096     // max candidates per row (WSB*WSEG)
#define WNB 4096
#define WCPAD 32      // counter stride in u32 (128B: one cache line per row)
#define T0KEY 0xC0000000u  // f2key(+2.0f): speculative raw-logit threshold

__device__ __forceinline__ unsigned w_f2key(float f) {
  unsigned u = __float_as_uint(f);
  return (u & 0x80000000u) ? ~u : (u | 0x80000000u);
}
__device__ __forceinline__ float w_key2f(unsigned k) {
  unsigned u = (k & 0x80000000u) ? (k & 0x7FFFFFFFu) : ~k;
  return __uint_as_float(u);
}
// Finite as fp32 AND as both bf16 halves (harness reads output as bf16).
__device__ __forceinline__ float w_dualfinite(float x) {
  unsigned u = __float_as_uint(x);
  if ((u & 0x7F800000u) == 0x7F800000u) u = 0xFF7F0000u;
  return __uint_as_float(u & 0xFFFF0000u);
}
__device__ __forceinline__ unsigned long long w_pfx(unsigned long long v,
                                                    int lane) {
  for (int d = 1; d < 64; d <<= 1) {
    unsigned long long o = __shfl_up(v, d);
    if (lane >= d) v += o;
  }
  return v;
}
__device__ __forceinline__ unsigned long long w_red(unsigned long long v) {
  for (int d = 32; d > 0; d >>= 1) v += __shfl_down(v, d);
  return v;  // lane 0 holds the sum
}
// fixed-point exp (scale 2^30): deterministic integer accumulation
__device__ __forceinline__ unsigned long long w_efix(unsigned key, float maxv,
                                                     float r) {
  float e = expf((w_key2f(key) - maxv) * r);
  return (unsigned long long)(e * 1073741824.0f);
}

// ---------------------------------------------------------------------------
// K1: streaming speculative gather. Per-(row,blk) private count slot (plain
// store -> no init kernel) and private global candidate segment (no global
// atomics anywhere). 2x-unrolled float4 loads for MLP.
// ---------------------------------------------------------------------------
__global__ __launch_bounds__(GTPB) void g14_gather(
    const float* __restrict__ logits, unsigned* __restrict__ cnt,
    unsigned long long* __restrict__ gcand, int V4) {
  __shared__ unsigned long long cbuf[WSEG];
  __shared__ unsigned ccnt;
  const int row = blockIdx.y;
  const int blk = blockIdx.x;
  const int tid = threadIdx.x;
  if (tid == 0) ccnt = 0u;
  __syncthreads();
  const int per = V4 / WSB;  // V4 divisible by 4 here (32000/4=8000)
  const int lo = blk * per;
  const int hi = (blk == WSB - 1) ? V4 : lo + per;
  const float4* l4 = reinterpret_cast<const float4*>(logits) + (size_t)row * V4;

#define G14_PROC(vv, ii)                                                      \
  {                                                                           \
    const unsigned basei = (unsigned)((ii) << 2);                             \
    unsigned key;                                                             \
    key = w_f2key((vv).x);                                                    \
    if (key >= T0KEY) {                                                       \
      unsigned pos = atomicAdd(&ccnt, 1u);                                    \
      if (pos < WSEG) cbuf[pos] = ((unsigned long long)key << 32) | basei;    \
    }                                                                         \
    key = w_f2key((vv).y);                                                    \
    if (key >= T0KEY) {                                                       \
      unsigned pos = atomicAdd(&ccnt, 1u);                                    \
      if (pos < WSEG) cbuf[pos] = ((unsigned long long)key << 32) | (basei + 1u); \
    }                                                                         \
    key = w_f2key((vv).z);                                                    \
    if (key >= T0KEY) {                                                       \
      unsigned pos = atomicAdd(&ccnt, 1u);                                    \
      if (pos < WSEG) cbuf[pos] = ((unsigned long long)key << 32) | (basei + 2u); \
    }                                                                         \
    key = w_f2key((vv).w);                                                    \
    if (key >= T0KEY) {                                                       \
      unsigned pos = atomicAdd(&ccnt, 1u);                                    \
      if (pos < WSEG) cbuf[pos] = ((unsigned long long)key << 32) | (basei + 3u); \
    }                                                                         \
  }

  int i = lo + tid;
  for (; i + GTPB < hi; i += 2 * GTPB) {
    float4 v0 = l4[i];
    float4 v1 = l4[i + GTPB];
    G14_PROC(v0, i);
    G14_PROC(v1, i + GTPB);
  }
  if (i < hi) {
    float4 v0 = l4[i];
    G14_PROC(v0, i);
  }
#undef G14_PROC
  __syncthreads();
  const unsigned cn = ccnt;
  if (tid == 0) cnt[row * WCPAD + blk] = cn;  // raw count; >WSEG => overflow
  const unsigned cw = (cn > WSEG) ? WSEG : cn;
  unsigned long long* gc = gcand + (size_t)row * WBUF + (size_t)blk * WSEG;
  for (unsigned j = tid; j < cw; j += GTPB) gc[j] = cbuf[j];
}

// ---------------------------------------------------------------------------
// K2: fused finish. Fast path: sort-free multi-level histogram descends on
// the segmented candidate set (count-rank for vkey; fixed-point exp-prefix
// for the top-p crossing). On any failure -> inline exact radix select +
// bitonic tail over the full row.
// ---------------------------------------------------------------------------
__global__ __launch_bounds__(FTPB) void g14_finish(
    const float* __restrict__ logits,
    const unsigned long long* __restrict__ gcand,
    const unsigned* __restrict__ cnt, const float* __restrict__ temps,
    const int* __restrict__ ks, const float* __restrict__ ps,
    unsigned long long* __restrict__ cutp, int V) {
  union ShU {
    struct { unsigned long long H[WNB]; unsigned long long H1[1024]; } f;
    struct {
      union { unsigned sel[2 * WNB]; unsigned long long buf[WBUF]; } u;
      float csum[WBUF];
    } fb;
  };
  __shared__ ShU sh;
  __shared__ unsigned long long G[64];
  __shared__ unsigned tieidx[256];
  __shared__ float wsum[16];
  __shared__ struct {
    unsigned flag, maxkey, b0, b1, vkey, b0c, b1c, kc, tcnt, cutidx, mreq;
    int selg;
    unsigned long long rank, resid, T, tot;
  } sc;
  __shared__ unsigned s_cnt, sh_prefix;
  __shared__ int sh_kk, s_j0, s_c;

  const int row = blockIdx.x;
  const int tid = threadIdx.x;
  const int lane = tid & 63;
  const int wv = tid >> 6;
  int k = ks[row];
  if (k < 1) k = 1;
  if (k > V) k = V;
  const float p = ps[row];
  const float r = 1.0f / temps[row];

  int segc[WSB];
  bool bad = false;
  int n = 0;
#pragma unroll
  for (int s = 0; s < WSB; ++s) {
    unsigned c = cnt[row * WCPAD + s];
    if (c > WSEG) { bad = true; c = WSEG; }
    segc[s] = (int)c;
    n += (int)c;
  }
  if (n < k || n < 1) bad = true;
  const unsigned long long* gc = gcand + (size_t)row * WBUF;

#define FOR_CANDS(VAR, BODY)                                                  \
  for (int _s = 0; _s < WSB; ++_s) {                                          \
    const unsigned long long* _seg = gc + _s * WSEG;                          \
    const int _cs = segc[_s];                                                 \
    for (int _i = tid; _i < _cs; _i += FTPB) {                                \
      unsigned long long VAR = _seg[_i];                                      \
      BODY                                                                    \
    }                                                                         \
  }

  if (!bad) do {  // fast path; break on failure -> fallback
    if (tid == 0) sc.flag = 0u;
    // ---- pass A: L0 count hist + row max key ----
    for (int i = tid; i < WNB; i += FTPB) sh.f.H[i] = 0ull;
    __syncthreads();
    unsigned mk = 0u;
    FOR_CANDS(e, {
      unsigned key = (unsigned)(e >> 32);
      atomicAdd(&sh.f.H[key >> 20], 1ull);
      if (key > mk) mk = key;
    });
    for (int d = 32; d > 0; d >>= 1) {
      unsigned o = __shfl_down(mk, d);
      if (o > mk) mk = o;
    }
    if (lane == 0) G[wv] = mk;
    __syncthreads();
    if (wv == 0) {
      unsigned m2 = (lane < 16) ? (unsigned)G[lane] : 0u;
      for (int d = 32; d > 0; d >>= 1) {
        unsigned o = __shfl_down(m2, d);
        if (o > m2) m2 = o;
      }
      if (lane == 0) sc.maxkey = m2;
    }
    __syncthreads();
    const float maxv = w_key2f(sc.maxkey);

    // ---- L0 cnt descend (suffix rank k) ----
    for (int q = 0; q < 4; ++q) {
      int g = wv * 4 + q;
      unsigned long long s = w_red(sh.f.H[g * 64 + lane]);
      if (lane == 0) G[g] = s;
    }
    __syncthreads();
    if (wv == 0) {
      unsigned long long pf = w_pfx(G[63 - lane], lane);
      int L = __ffsll(__ballot(pf >= (unsigned long long)k)) - 1;
      unsigned long long above = (L > 0) ? __shfl(pf, L - 1) : 0ull;
      if (lane == 0) { sc.selg = 63 - L; sc.rank = (unsigned long long)k - above; }
    }
    __syncthreads();
    if (wv == 0) {
      int g = sc.selg;
      unsigned long long pf = w_pfx(sh.f.H[g * 64 + (63 - lane)], lane);
      int L = __ffsll(__ballot(pf >= sc.rank)) - 1;
      unsigned long long above = (L > 0) ? __shfl(pf, L - 1) : 0ull;
      if (lane == 0) { sc.b0 = g * 64 + (63 - L); sc.rank = sc.rank - above; }
    }
    __syncthreads();
    // ---- L1 cnt ----
    for (int i = tid; i < 1024; i += FTPB) sh.f.H1[i] = 0ull;
    __syncthreads();
    {
      const unsigned b0 = sc.b0;
      FOR_CANDS(e, {
        unsigned key = (unsigned)(e >> 32);
        if ((key >> 20) == b0) atomicAdd(&sh.f.H1[(key >> 10) & 1023u], 1ull);
      });
    }
    __syncthreads();
    {
      unsigned long long s = w_red(sh.f.H1[wv * 64 + lane]);
      if (lane == 0) G[wv] = s;
    }
    __syncthreads();
    if (wv == 0) {
      unsigned long long gv = (lane < 16) ? G[15 - lane] : 0ull;
      unsigned long long pf = w_pfx(gv, lane);
      int L = __ffsll(__ballot((lane < 16) && (pf >= sc.rank))) - 1;
      unsigned long long above = (L > 0) ? __shfl(pf, L - 1) : 0ull;
      if (lane == 0) { sc.selg = 15 - L; sc.rank = sc.rank - above; }
    }
    __syncthreads();
    if (wv == 0) {
      int g = sc.selg;
      unsigned long long pf = w_pfx(sh.f.H1[g * 64 + (63 - lane)], lane);
      int L = __ffsll(__ballot(pf >= sc.rank)) - 1;
      unsigned long long above = (L > 0) ? __shfl(pf, L - 1) : 0ull;
      if (lane == 0) { sc.b1 = g * 64 + (63 - L); sc.rank = sc.rank - above; }
    }
    __syncthreads();
    // ---- L2 cnt -> vkey ----
    for (int i = tid; i < 1024; i += FTPB) sh.f.H1[i] = 0ull;
    __syncthreads();
    {
      const unsigned pref = (sc.b0 << 10) | sc.b1;
      FOR_CANDS(e, {
        unsigned key = (unsigned)(e >> 32);
        if ((key >> 10) == pref) atomicAdd(&sh.f.H1[key & 1023u], 1ull);
      });
    }
    __syncthreads();
    {
      unsigned long long s = w_red(sh.f.H1[wv * 64 + lane]);
      if (lane == 0) G[wv] = s;
    }
    __syncthreads();
    if (wv == 0) {
      unsigned long long gv = (lane < 16) ? G[15 - lane] : 0ull;
      unsigned long long pf = w_pfx(gv, lane);
      int L = __ffsll(__ballot((lane < 16) && (pf >= sc.rank))) - 1;
      unsigned long long above = (L > 0) ? __shfl(pf, L - 1) : 0ull;
      if (lane == 0) { sc.selg = 15 - L; sc.rank = sc.rank - above; }
    }
    __syncthreads();
    if (wv == 0) {
      int g = sc.selg;
      unsigned long long pf = w_pfx(sh.f.H1[g * 64 + (63 - lane)], lane);
      int L = __ffsll(__ballot(pf >= sc.rank)) - 1;
      if (lane == 0)
        sc.vkey = (sc.b0 << 20) | (sc.b1 << 10) | (g * 64 + (63 - L));
    }
    __syncthreads();
    const unsigned vkey = sc.vkey;

    // ---- base (e-sum below vkey) and total ----
    {
      unsigned long long tb = 0ull, tt = 0ull;
      FOR_CANDS(e, {
        unsigned key = (unsigned)(e >> 32);
        unsigned long long ef = w_efix(key, maxv, r);
        tt += ef;
        if (key < vkey) tb += ef;
      });
      tt = w_red(tt);
      tb = w_red(tb);
      if (lane == 0) { G[wv] = tt; G[16 + wv] = tb; }
    }
    __syncthreads();
    if (wv == 0) {
      unsigned long long tt = w_red((lane < 16) ? G[lane] : 0ull);
      unsigned long long tb = w_red((lane < 16) ? G[16 + lane] : 0ull);
      if (lane == 0) {
        sc.tot = tt;
        unsigned long long Z = tt - tb;
        if (Z == 0ull) sc.flag = 1u;
        else {
          unsigned long long T =
              tb + (unsigned long long)((double)(1.0f - p) * (double)Z);
          if (T >= tt) sc.flag = 1u;
          sc.T = T;
        }
      }
    }
    __syncthreads();
    if (sc.flag) break;
    // ---- L0 sum descend (ascending prefix vs T) ----
    for (int i = tid; i < WNB; i += FTPB) sh.f.H[i] = 0ull;
    __syncthreads();
    FOR_CANDS(e, {
      unsigned key = (unsigned)(e >> 32);
      atomicAdd(&sh.f.H[key >> 20], w_efix(key, maxv, r));
    });
    __syncthreads();
    for (int q = 0; q < 4; ++q) {
      int g = wv * 4 + q;
      unsigned long long s = w_red(sh.f.H[g * 64 + lane]);
      if (lane == 0) G[g] = s;
    }
    __syncthreads();
    if (wv == 0) {
      unsigned long long pf = w_pfx(G[lane], lane);
      int L = __ffsll(__ballot(pf > sc.T)) - 1;
      unsigned long long excl = (L > 0) ? __shfl(pf, L - 1) : 0ull;
      if (lane == 0) { sc.selg = L; sc.resid = sc.T - excl; }
    }
    __syncthreads();
    if (wv == 0) {
      int g = sc.selg;
      unsigned long long pf = w_pfx(sh.f.H[g * 64 + lane], lane);
      int L = __ffsll(__ballot(pf > sc.resid)) - 1;
      unsigned long long excl = (L > 0) ? __shfl(pf, L - 1) : 0ull;
      if (lane == 0) { sc.b0c = g * 64 + L; sc.resid = sc.resid - excl; }
    }
    __syncthreads();
    // ---- L1 sum ----
    for (int i = tid; i < 1024; i += FTPB) sh.f.H1[i] = 0ull;
    __syncthreads();
    {
      const unsigned b0 = sc.b0c;
      FOR_CANDS(e, {
        unsigned key = (unsigned)(e >> 32);
        if ((key >> 20) == b0)
          atomicAdd(&sh.f.H1[(key >> 10) & 1023u], w_efix(key, maxv, r));
      });
    }
    __syncthreads();
    {
      unsigned long long s = w_red(sh.f.H1[wv * 64 + lane]);
      if (lane == 0) G[wv] = s;
    }
    __syncthreads();
    if (wv == 0) {
      unsigned long long gv = (lane < 16) ? G[lane] : 0ull;
      unsigned long long pf = w_pfx(gv, lane);
      int L = __ffsll(__ballot((lane < 16) && (pf > sc.resid))) - 1;
      unsigned long long excl = (L > 0) ? __shfl(pf, L - 1) : 0ull;
      if (lane == 0) { sc.selg = L; sc.resid = sc.resid - excl; }
    }
    __syncthreads();
    if (wv == 0) {
      int g = sc.selg;
      unsigned long long pf = w_pfx(sh.f.H1[g * 64 + lane], lane);
      int L = __ffsll(__ballot(pf > sc.resid)) - 1;
      unsigned long long excl = (L > 0) ? __shfl(pf, L - 1) : 0ull;
      if (lane == 0) { sc.b1c = g * 64 + L; sc.resid = sc.resid - excl; }
    }
    __syncthreads();
    // ---- L2 sum -> crossing key ----
    for (int i = tid; i < 1024; i += FTPB) sh.f.H1[i] = 0ull;
    __syncthreads();
    {
      const unsigned pref = (sc.b0c << 10) | sc.b1c;
      FOR_CANDS(e, {
        unsigned key = (unsigned)(e >> 32);
        if ((key >> 10) == pref)
          atomicAdd(&sh.f.H1[key & 1023u], w_efix(key, maxv, r));
      });
    }
    __syncthreads();
    {
      unsigned long long s = w_red(sh.f.H1[wv * 64 + lane]);
      if (lane == 0) G[wv] = s;
    }
    __syncthreads();
    if (wv == 0) {
      unsigned long long gv = (lane < 16) ? G[lane] : 0ull;
      unsigned long long pf = w_pfx(gv, lane);
      int L = __ffsll(__ballot((lane < 16) && (pf > sc.resid))) - 1;
      unsigned long long excl = (L > 0) ? __shfl(pf, L - 1) : 0ull;
      if (lane == 0) { sc.selg = L; sc.resid = sc.resid - excl; }
    }
    __syncthreads();
    if (wv == 0) {
      int g = sc.selg;
      unsigned long long pf = w_pfx(sh.f.H1[g * 64 + lane], lane);
      int L = __ffsll(__ballot(pf > sc.resid)) - 1;
      unsigned long long excl = (L > 0) ? __shfl(pf, L - 1) : 0ull;
      if (lane == 0) {
        sc.kc = (sc.b0c << 20) | (sc.b1c << 10) | (unsigned)(g * 64 + L);
        sc.resid = sc.resid - excl;
      }
    }
    __syncthreads();
    const unsigned kc = sc.kc;
    {
      unsigned long long ek = w_efix(kc, maxv, r);
      if (tid == 0) {
        if (ek == 0ull) sc.flag = 1u;
        else sc.mreq = (unsigned)(sc.resid / ek + 1ull);
        sc.tcnt = 0u;
      }
    }
    __syncthreads();
    if (sc.flag) break;
    // ---- tie group at kc: pick mreq-th smallest index ----
    FOR_CANDS(e, {
      if ((unsigned)(e >> 32) == kc) {
        unsigned pos = atomicAdd(&sc.tcnt, 1u);
        if (pos < 256u) tieidx[pos] = (unsigned)(e & 0xFFFFFFFFu);
      }
    });
    __syncthreads();
    const unsigned t = sc.tcnt;
    if (t > 256u || sc.mreq > t) {
      if (tid == 0) sc.flag = 1u;
      __syncthreads();
      break;
    }
    if (tid < (int)t) {
      unsigned my = tieidx[tid];
      unsigned rank = 0;
      for (unsigned j = 0; j < t; ++j) rank += (tieidx[j] < my) ? 1u : 0u;
      if (rank == sc.mreq - 1u) sc.cutidx = my;
    }
    __syncthreads();
    if (tid == 0) cutp[row] = ((unsigned long long)kc << 32) | sc.cutidx;
    return;
  } while (0);
#undef FOR_CANDS

  // ===================== exact fallback (rare/adversarial) ==================
  {
    const float4* l4 =
        reinterpret_cast<const float4*>(logits + (size_t)row * (size_t)V);
    const int V4 = V >> 2;
    unsigned prefix = 0;
    int kk = k;
    for (int lvl = 0; lvl < 3; ++lvl) {
      const int shift = (lvl == 0) ? 20 : (lvl == 1) ? 8 : 0;
      const int nb = (lvl == 2) ? 256 : 4096;
      for (int i = tid; i < 2 * WNB; i += FTPB) sh.fb.u.sel[i] = 0;
      __syncthreads();
      if (lvl == 0) {
        for (int i = tid; i < V4; i += FTPB) {
          float4 v = l4[i];
          atomicAdd(&sh.fb.u.sel[w_f2key(v.x) >> 20], 1u);
          atomicAdd(&sh.fb.u.sel[w_f2key(v.y) >> 20], 1u);
          atomicAdd(&sh.fb.u.sel[w_f2key(v.z) >> 20], 1u);
          atomicAdd(&sh.fb.u.sel[w_f2key(v.w) >> 20], 1u);
        }
      } else {
        const int hs = (lvl == 1) ? 20 : 8;
        const unsigned want = prefix >> hs;
        const unsigned bmask = (unsigned)(nb - 1);
        for (int i = tid; i < V4; i += FTPB) {
          float4 v = l4[i];
          unsigned key;
          key = w_f2key(v.x);
          if ((key >> hs) == want) atomicAdd(&sh.fb.u.sel[(key >> shift) & bmask], 1u);
          key = w_f2key(v.y);
          if ((key >> hs) == want) atomicAdd(&sh.fb.u.sel[(key >> shift) & bmask], 1u);
          key = w_f2key(v.z);
          if ((key >> hs) == want) atomicAdd(&sh.fb.u.sel[(key >> shift) & bmask], 1u);
          key = w_f2key(v.w);
          if ((key >> hs) == want) atomicAdd(&sh.fb.u.sel[(key >> shift) & bmask], 1u);
        }
      }
      __syncthreads();
      if (tid == 0) {
        int acc = 0;
        sh_prefix = prefix;
        sh_kk = kk;
        for (int b = nb - 1; b >= 0; --b) {
          int h = (int)sh.fb.u.sel[b];
          if (acc + h >= kk) {
            sh_kk = kk - acc;
            sh_prefix = prefix | ((unsigned)b << shift);
            break;
          }
          acc += h;
        }
      }
      __syncthreads();
      prefix = sh_prefix;
      kk = sh_kk;
      __syncthreads();
      if (lvl == 2) break;
      if (tid == 0) s_cnt = 0;
      __syncthreads();
      for (int i = tid; i < V4; i += FTPB) {
        float4 v = l4[i];
        unsigned c = (w_f2key(v.x) >= prefix) + (w_f2key(v.y) >= prefix) +
                     (w_f2key(v.z) >= prefix) + (w_f2key(v.w) >= prefix);
        if (c) atomicAdd(&s_cnt, c);
      }
      __syncthreads();
      if (s_cnt <= (unsigned)WBUF) break;
      __syncthreads();
    }
    const unsigned thr = prefix;

    if (tid == 0) s_cnt = 0;
    __syncthreads();
    for (int i = tid; i < V4; i += FTPB) {
      float4 v = l4[i];
      const unsigned basei = (unsigned)(i << 2);
      unsigned key;
      key = w_f2key(v.x);
      if (key >= thr) {
        unsigned pos = atomicAdd(&s_cnt, 1u);
        if (pos < WBUF) sh.fb.u.buf[pos] = ((unsigned long long)key << 32) | basei;
      }
      key = w_f2key(v.y);
      if (key >= thr) {
        unsigned pos = atomicAdd(&s_cnt, 1u);
        if (pos < WBUF)
          sh.fb.u.buf[pos] = ((unsigned long long)key << 32) | (basei + 1u);
      }
      key = w_f2key(v.z);
      if (key >= thr) {
        unsigned pos = atomicAdd(&s_cnt, 1u);
        if (pos < WBUF)
          sh.fb.u.buf[pos] = ((unsigned long long)key << 32) | (basei + 2u);
      }
      key = w_f2key(v.w);
      if (key >= thr) {
        unsigned pos = atomicAdd(&s_cnt, 1u);
        if (pos < WBUF)
          sh.fb.u.buf[pos] = ((unsigned long long)key << 32) | (basei + 3u);
      }
    }
    __syncthreads();
    int nn = (int)s_cnt;
    if (nn > WBUF) nn = WBUF;
    if (nn < 1) nn = 1;

    int m = 64;
    while (m < nn) m <<= 1;
    for (int i = nn + tid; i < m; i += FTPB)
      sh.fb.u.buf[i] = 0xFFFFFFFFFFFFFFFFull;
    __syncthreads();
    for (int size = 2; size <= m; size <<= 1) {
      for (int stride = size >> 1; stride > 0; stride >>= 1) {
        if (stride >= 32) __syncthreads();
        else __asm__ volatile("" ::: "memory");
        for (int i = tid; i < m; i += FTPB) {
          int j = i ^ stride;
          if (j > i) {
            unsigned long long a = sh.fb.u.buf[i], bb = sh.fb.u.buf[j];
            bool up = ((i & size) == 0);
            if (up ? (a > bb) : (a < bb)) { sh.fb.u.buf[i] = bb; sh.fb.u.buf[j] = a; }
          }
        }
      }
    }
    __syncthreads();

    const float maxv = w_key2f((unsigned)(sh.fb.u.buf[nn - 1] >> 32)) * r;
    const int i0 = tid << 2;
    float e0 = 0.f, e1 = 0.f, e2 = 0.f, e3 = 0.f;
    if (i0 < nn)
      e0 = expf(w_key2f((unsigned)(sh.fb.u.buf[i0] >> 32)) * r - maxv);
    if (i0 + 1 < nn)
      e1 = expf(w_key2f((unsigned)(sh.fb.u.buf[i0 + 1] >> 32)) * r - maxv);
    if (i0 + 2 < nn)
      e2 = expf(w_key2f((unsigned)(sh.fb.u.buf[i0 + 2] >> 32)) * r - maxv);
    if (i0 + 3 < nn)
      e3 = expf(w_key2f((unsigned)(sh.fb.u.buf[i0 + 3] >> 32)) * r - maxv);
    const float lsum = e0 + e1 + e2 + e3;
    float vincl = lsum;
    for (int d = 1; d < 64; d <<= 1) {
      float o = __shfl_up(vincl, d);
      if (lane >= d) vincl += o;
    }
    if (lane == 63) wsum[wv] = vincl;
    __syncthreads();
    if (wv == 0 && lane < 16) {
      float s = wsum[lane];
      for (int d = 1; d < 16; d <<= 1) {
        float o = __shfl_up(s, d);
        if (lane >= d) s += o;
      }
      wsum[lane] = s;
    }
    __syncthreads();
    {
      float rr = (wv > 0 ? wsum[wv - 1] : 0.0f) + (vincl - lsum);
      rr += e0; if (i0 < nn)     sh.fb.csum[i0] = rr;
      rr += e1; if (i0 + 1 < nn) sh.fb.csum[i0 + 1] = rr;
      rr += e2; if (i0 + 2 < nn) sh.fb.csum[i0 + 2] = rr;
      rr += e3; if (i0 + 3 < nn) sh.fb.csum[i0 + 3] = rr;
    }
    __syncthreads();

    const int k_eff = (k < nn) ? k : nn;
    const unsigned vkey = (unsigned)(sh.fb.u.buf[nn - k_eff] >> 32);
    if (tid == 0) { s_j0 = 0; s_c = nn - 1; }
    __syncthreads();
    for (int i = tid; i < nn; i += FTPB) {
      unsigned ki = (unsigned)(sh.fb.u.buf[i] >> 32);
      if (ki == vkey && (i == 0 || (unsigned)(sh.fb.u.buf[i - 1] >> 32) != vkey))
        s_j0 = i;
    }
    __syncthreads();
    const int j0 = s_j0;
    const float base = (j0 > 0) ? sh.fb.csum[j0 - 1] : 0.0f;
    const float Z = sh.fb.csum[nn - 1] - base;
    const float thrp = (1.0f - p) * Z;
    for (int i = j0 + tid; i < nn; i += FTPB) {
      if (sh.fb.csum[i] - base > thrp) atomicMin(&s_c, i);
    }
    __syncthreads();
    if (tid == 0) cutp[row] = sh.fb.u.buf[s_c];
  }
}

// ---------------------------------------------------------------------------
// K3: fat apply; sole writer of final d_out; dual-finite everywhere.
// ---------------------------------------------------------------------------
__global__ void g14_apply(const float* __restrict__ logits,
                          const float* __restrict__ temps,
                          const unsigned long long* __restrict__ cutp,
                          float* __restrict__ out, int V4) {
  const int row = blockIdx.y;
  const int i = blockIdx.x * blockDim.x + threadIdx.x;
  if (i >= V4) return;
  const float r = 1.0f / temps[row];
  const unsigned long long cutoff = cutp[row];
  const size_t base = (size_t)row * (size_t)V4 + i;
  float4 v = reinterpret_cast<const float4*>(logits)[base];
  const float NEG = __uint_as_float(0xFF7F0000u);
  const unsigned e = (unsigned)(i << 2);
  unsigned long long k0 = ((unsigned long long)w_f2key(v.x) << 32) | e;
  unsigned long long k1 = ((unsigned long long)w_f2key(v.y) << 32) | (e + 1u);
  unsigned long long k2 = ((unsigned long long)w_f2key(v.z) << 32) | (e + 2u);
  unsigned long long k3 = ((unsigned long long)w_f2key(v.w) << 32) | (e + 3u);
  v.x = (k0 >= cutoff) ? w_dualfinite(v.x * r) : NEG;
  v.y = (k1 >= cutoff) ? w_dualfinite(v.y * r) : NEG;
  v.z = (k2 >= cutoff) ? w_dualfinite(v.z * r) : NEG;
  v.w = (k3 >= cutoff) ? w_dualfinite(v.w * r) : NEG;
  reinterpret_cast<float4*>(out)[base] = v;
}

extern "C" void kernel_launch(void* const* d_in, const int* in_sizes, int n_in,
                              void* d_out, int out_size, void* d_ws, size_t ws_size,
                              hipStream_t stream) {
  const float* logits = (const float*)d_in[0];
  const float* temps  = (const float*)d_in[1];
  const int*   ks     = (const int*)d_in[2];
  const float* ps     = (const float*)d_in[3];
  float* out = (float*)d_out;

  const int B = in_sizes[1];
  const int V = in_sizes[0] / B;
  const int V4 = V >> 2;

  // d_ws: cnt[B*WCPAD] u32 | cutp[B] u64 | gcand[B*WBUF] u64
  unsigned* cnt = (unsigned*)d_ws;
  unsigned long long* cutp = (unsigned long long*)(cnt + (size_t)B * WCPAD);
  unsigned long long* gcand = cutp + B;

  dim3 gg(WSB, B);
  g14_gather<<<gg, GTPB, 0, stream>>>(logits, cnt, gcand, V4);
  g14_finish<<<B, FTPB, 0, stream>>>(logits, gcand, cnt, temps, ks, ps, cutp, V);
  dim3 ga((V4 + 255) / 256, B);
  g14_apply<<<ga, 256, 0, stream>>>(logits, temps, cutp, out, V4);
}

// Round 15
// 85.437 us; speedup vs baseline: 27.4277x; 1.0292x over previous
//
#include <hip/hip_runtime.h>
#include <math.h>
#include <float.h>

#define GTPB 512      // gather block size
#define FTPB 1024     // finish block size
#define WSB 4         // gather blocks per row
#define WSEG 1024     // per-block candidate segment
#define WBUF 4096     // max candidates per row (WSB*WSEG)
#define WNB 4096
#define WCPAD 32      // counter stride in u32 (128B: one cache line per row)
#define T0KEY 0xC0000000u  // f2key(+2.0f): speculative raw-logit threshold
#define NEGBITS 0xFF7F0000u

__device__ __forceinline__ unsigned w_f2key(float f) {
  unsigned u = __float_as_uint(f);
  return (u & 0x80000000u) ? ~u : (u | 0x80000000u);
}
__device__ __forceinline__ float w_key2f(unsigned k) {
  unsigned u = (k & 0x80000000u) ? (k & 0x7FFFFFFFu) : ~k;
  return __uint_as_float(u);
}
// Finite as fp32 AND as both bf16 halves (harness reads output as bf16).
__device__ __forceinline__ float w_dualfinite(float x) {
  unsigned u = __float_as_uint(x);
  if ((u & 0x7F800000u) == 0x7F800000u) u = NEGBITS;
  return __uint_as_float(u & 0xFFFF0000u);
}
__device__ __forceinline__ unsigned long long w_pfx(unsigned long long v,
                                                    int lane) {
  for (int d = 1; d < 64; d <<= 1) {
    unsigned long long o = __shfl_up(v, d);
    if (lane >= d) v += o;
  }
  return v;
}
__device__ __forceinline__ unsigned long long w_red(unsigned long long v) {
  for (int d = 32; d > 0; d >>= 1) v += __shfl_down(v, d);
  return v;  // lane 0 holds the sum
}
// fixed-point exp (scale 2^30): deterministic integer accumulation
__device__ __forceinline__ unsigned long long w_efix(unsigned key, float maxv,
                                                     float r) {
  float e = expf((w_key2f(key) - maxv) * r);
  return (unsigned long long)(e * 1073741824.0f);
}

// ---------------------------------------------------------------------------
// K1: single streaming pass. Stages candidates (key >= T0) to private global
// segments AND prefills the ENTIRE output row with NEG (valid because, when
// the speculative path succeeds, the survivor cutoff >= k-th-largest >= T0,
// so all sub-T0 positions are masked; candidate positions are corrected by
// K2's scatter; flagged rows are fully rewritten by the fallback).
// ---------------------------------------------------------------------------
__global__ __launch_bounds__(GTPB) void g15_gather(
    const float* __restrict__ logits, float* __restrict__ out,
    unsigned* __restrict__ cnt, unsigned long long* __restrict__ gcand,
    int V4) {
  __shared__ unsigned long long cbuf[WSEG];
  __shared__ unsigned ccnt;
  const int row = blockIdx.y;
  const int blk = blockIdx.x;
  const int tid = threadIdx.x;
  if (tid == 0) ccnt = 0u;
  __syncthreads();
  const int per = V4 / WSB;
  const int lo = blk * per;
  const int hi = (blk == WSB - 1) ? V4 : lo + per;
  const float4* l4 = reinterpret_cast<const float4*>(logits) + (size_t)row * V4;
  float4* o4 = reinterpret_cast<float4*>(out) + (size_t)row * V4;
  const float NEG = __uint_as_float(NEGBITS);
  const float4 neg4 = make_float4(NEG, NEG, NEG, NEG);

#define G15_PROC(vv, ii)                                                      \
  {                                                                           \
    const unsigned basei = (unsigned)((ii) << 2);                             \
    unsigned key;                                                             \
    key = w_f2key((vv).x);                                                    \
    if (key >= T0KEY) {                                                       \
      unsigned pos = atomicAdd(&ccnt, 1u);                                    \
      if (pos < WSEG) cbuf[pos] = ((unsigned long long)key << 32) | basei;    \
    }                                                                         \
    key = w_f2key((vv).y);                                                    \
    if (key >= T0KEY) {                                                       \
      unsigned pos = atomicAdd(&ccnt, 1u);                                    \
      if (pos < WSEG) cbuf[pos] = ((unsigned long long)key << 32) | (basei + 1u); \
    }                                                                         \
    key = w_f2key((vv).z);                                                    \
    if (key >= T0KEY) {                                                       \
      unsigned pos = atomicAdd(&ccnt, 1u);                                    \
      if (pos < WSEG) cbuf[pos] = ((unsigned long long)key << 32) | (basei + 2u); \
    }                                                                         \
    key = w_f2key((vv).w);                                                    \
    if (key >= T0KEY) {                                                       \
      unsigned pos = atomicAdd(&ccnt, 1u);                                    \
      if (pos < WSEG) cbuf[pos] = ((unsigned long long)key << 32) | (basei + 3u); \
    }                                                                         \
  }

  int i = lo + tid;
  for (; i + GTPB < hi; i += 2 * GTPB) {
    float4 v0 = l4[i];
    float4 v1 = l4[i + GTPB];
    o4[i] = neg4;
    o4[i + GTPB] = neg4;
    G15_PROC(v0, i);
    G15_PROC(v1, i + GTPB);
  }
  if (i < hi) {
    float4 v0 = l4[i];
    o4[i] = neg4;
    G15_PROC(v0, i);
  }
#undef G15_PROC
  __syncthreads();
  const unsigned cn = ccnt;
  if (tid == 0) cnt[row * WCPAD + blk] = cn;  // raw count; >WSEG => overflow
  const unsigned cw = (cn > WSEG) ? WSEG : cn;
  unsigned long long* gc = gcand + (size_t)row * WBUF + (size_t)blk * WSEG;
  for (unsigned j = tid; j < cw; j += GTPB) gc[j] = cbuf[j];
}

// ---------------------------------------------------------------------------
// K2: fused finish + scatter. Fast path: sort-free multi-level histogram
// descends (count-rank for vkey; fixed-point exp-prefix for the top-p
// crossing) -> 64-bit packed cutoff -> scatter-correct ONLY the candidate
// positions. Failure -> inline exact radix select + bitonic + full-row apply.
// ---------------------------------------------------------------------------
__global__ __launch_bounds__(FTPB) void g15_finish(
    const float* __restrict__ logits,
    const unsigned long long* __restrict__ gcand,
    const unsigned* __restrict__ cnt, const float* __restrict__ temps,
    const int* __restrict__ ks, const float* __restrict__ ps,
    float* __restrict__ out, int V) {
  union ShU {
    struct { unsigned long long H[WNB]; unsigned long long H1[1024]; } f;
    struct {
      union { unsigned sel[2 * WNB]; unsigned long long buf[WBUF]; } u;
      float csum[WBUF];
    } fb;
  };
  __shared__ ShU sh;
  __shared__ unsigned long long G[64];
  __shared__ unsigned tieidx[256];
  __shared__ float wsum[16];
  __shared__ struct {
    unsigned flag, maxkey, b0, b1, vkey, b0c, b1c, kc, tcnt, cutidx, mreq;
    int selg;
    unsigned long long rank, resid, T;
  } sc;
  __shared__ unsigned s_cnt, sh_prefix;
  __shared__ int sh_kk, s_j0, s_c;

  const int row = blockIdx.x;
  const int tid = threadIdx.x;
  const int lane = tid & 63;
  const int wv = tid >> 6;
  int k = ks[row];
  if (k < 1) k = 1;
  if (k > V) k = V;
  const float p = ps[row];
  const float r = 1.0f / temps[row];
  const float NEG = __uint_as_float(NEGBITS);
  float* orow = out + (size_t)row * (size_t)V;

  int segc[WSB];
  bool bad = false;
  int n = 0;
#pragma unroll
  for (int s = 0; s < WSB; ++s) {
    unsigned c = cnt[row * WCPAD + s];
    if (c > WSEG) { bad = true; c = WSEG; }
    segc[s] = (int)c;
    n += (int)c;
  }
  if (n < k || n < 1) bad = true;
  const unsigned long long* gc = gcand + (size_t)row * WBUF;

#define FOR_CANDS(VAR, BODY)                                                  \
  for (int _s = 0; _s < WSB; ++_s) {                                          \
    const unsigned long long* _seg = gc + _s * WSEG;                          \
    const int _cs = segc[_s];                                                 \
    for (int _i = tid; _i < _cs; _i += FTPB) {                                \
      unsigned long long VAR = _seg[_i];                                      \
      BODY                                                                    \
    }                                                                         \
  }

  if (!bad) do {  // fast path; break on failure -> exact fallback
    if (tid == 0) sc.flag = 0u;
    // ---- pass A: L0 count hist + row max key ----
    for (int i = tid; i < WNB; i += FTPB) sh.f.H[i] = 0ull;
    __syncthreads();
    unsigned mk = 0u;
    FOR_CANDS(e, {
      unsigned key = (unsigned)(e >> 32);
      atomicAdd(&sh.f.H[key >> 20], 1ull);
      if (key > mk) mk = key;
    });
    for (int d = 32; d > 0; d >>= 1) {
      unsigned o = __shfl_down(mk, d);
      if (o > mk) mk = o;
    }
    if (lane == 0) G[wv] = mk;
    __syncthreads();
    if (wv == 0) {
      unsigned m2 = (lane < 16) ? (unsigned)G[lane] : 0u;
      for (int d = 32; d > 0; d >>= 1) {
        unsigned o = __shfl_down(m2, d);
        if (o > m2) m2 = o;
      }
      if (lane == 0) sc.maxkey = m2;
    }
    __syncthreads();
    const float maxv = w_key2f(sc.maxkey);

    // ---- L0 cnt descend (suffix rank k) ----
    for (int q = 0; q < 4; ++q) {
      int g = wv * 4 + q;
      unsigned long long s = w_red(sh.f.H[g * 64 + lane]);
      if (lane == 0) G[g] = s;
    }
    __syncthreads();
    if (wv == 0) {
      unsigned long long pf = w_pfx(G[63 - lane], lane);
      int L = __ffsll(__ballot(pf >= (unsigned long long)k)) - 1;
      unsigned long long above = (L > 0) ? __shfl(pf, L - 1) : 0ull;
      if (lane == 0) { sc.selg = 63 - L; sc.rank = (unsigned long long)k - above; }
    }
    __syncthreads();
    if (wv == 0) {
      int g = sc.selg;
      unsigned long long pf = w_pfx(sh.f.H[g * 64 + (63 - lane)], lane);
      int L = __ffsll(__ballot(pf >= sc.rank)) - 1;
      unsigned long long above = (L > 0) ? __shfl(pf, L - 1) : 0ull;
      if (lane == 0) { sc.b0 = g * 64 + (63 - L); sc.rank = sc.rank - above; }
    }
    __syncthreads();
    // ---- L1 cnt ----
    for (int i = tid; i < 1024; i += FTPB) sh.f.H1[i] = 0ull;
    __syncthreads();
    {
      const unsigned b0 = sc.b0;
      FOR_CANDS(e, {
        unsigned key = (unsigned)(e >> 32);
        if ((key >> 20) == b0) atomicAdd(&sh.f.H1[(key >> 10) & 1023u], 1ull);
      });
    }
    __syncthreads();
    {
      unsigned long long s = w_red(sh.f.H1[wv * 64 + lane]);
      if (lane == 0) G[wv] = s;
    }
    __syncthreads();
    if (wv == 0) {
      unsigned long long gv = (lane < 16) ? G[15 - lane] : 0ull;
      unsigned long long pf = w_pfx(gv, lane);
      int L = __ffsll(__ballot((lane < 16) && (pf >= sc.rank))) - 1;
      unsigned long long above = (L > 0) ? __shfl(pf, L - 1) : 0ull;
      if (lane == 0) { sc.selg = 15 - L; sc.rank = sc.rank - above; }
    }
    __syncthreads();
    if (wv == 0) {
      int g = sc.selg;
      unsigned long long pf = w_pfx(sh.f.H1[g * 64 + (63 - lane)], lane);
      int L = __ffsll(__ballot(pf >= sc.rank)) - 1;
      unsigned long long above = (L > 0) ? __shfl(pf, L - 1) : 0ull;
      if (lane == 0) { sc.b1 = g * 64 + (63 - L); sc.rank = sc.rank - above; }
    }
    __syncthreads();
    // ---- L2 cnt -> vkey ----
    for (int i = tid; i < 1024; i += FTPB) sh.f.H1[i] = 0ull;
    __syncthreads();
    {
      const unsigned pref = (sc.b0 << 10) | sc.b1;
      FOR_CANDS(e, {
        unsigned key = (unsigned)(e >> 32);
        if ((key >> 10) == pref) atomicAdd(&sh.f.H1[key & 1023u], 1ull);
      });
    }
    __syncthreads();
    {
      unsigned long long s = w_red(sh.f.H1[wv * 64 + lane]);
      if (lane == 0) G[wv] = s;
    }
    __syncthreads();
    if (wv == 0) {
      unsigned long long gv = (lane < 16) ? G[15 - lane] : 0ull;
      unsigned long long pf = w_pfx(gv, lane);
      int L = __ffsll(__ballot((lane < 16) && (pf >= sc.rank))) - 1;
      unsigned long long above = (L > 0) ? __shfl(pf, L - 1) : 0ull;
      if (lane == 0) { sc.selg = 15 - L; sc.rank = sc.rank - above; }
    }
    __syncthreads();
    if (wv == 0) {
      int g = sc.selg;
      unsigned long long pf = w_pfx(sh.f.H1[g * 64 + (63 - lane)], lane);
      int L = __ffsll(__ballot(pf >= sc.rank)) - 1;
      if (lane == 0)
        sc.vkey = (sc.b0 << 20) | (sc.b1 << 10) | (g * 64 + (63 - L));
    }
    __syncthreads();
    const unsigned vkey = sc.vkey;

    // ---- base (e-sum below vkey) and total ----
    {
      unsigned long long tb = 0ull, tt = 0ull;
      FOR_CANDS(e, {
        unsigned key = (unsigned)(e >> 32);
        unsigned long long ef = w_efix(key, maxv, r);
        tt += ef;
        if (key < vkey) tb += ef;
      });
      tt = w_red(tt);
      tb = w_red(tb);
      if (lane == 0) { G[wv] = tt; G[16 + wv] = tb; }
    }
    __syncthreads();
    if (wv == 0) {
      unsigned long long tt = w_red((lane < 16) ? G[lane] : 0ull);
      unsigned long long tb = w_red((lane < 16) ? G[16 + lane] : 0ull);
      if (lane == 0) {
        unsigned long long Z = tt - tb;
        if (Z == 0ull) sc.flag = 1u;
        else {
          unsigned long long T =
              tb + (unsigned long long)((double)(1.0f - p) * (double)Z);
          if (T >= tt) sc.flag = 1u;
          sc.T = T;
        }
      }
    }
    __syncthreads();
    if (sc.flag) break;
    // ---- L0 sum descend (ascending prefix vs T) ----
    for (int i = tid; i < WNB; i += FTPB) sh.f.H[i] = 0ull;
    __syncthreads();
    FOR_CANDS(e, {
      unsigned key = (unsigned)(e >> 32);
      atomicAdd(&sh.f.H[key >> 20], w_efix(key, maxv, r));
    });
    __syncthreads();
    for (int q = 0; q < 4; ++q) {
      int g = wv * 4 + q;
      unsigned long long s = w_red(sh.f.H[g * 64 + lane]);
      if (lane == 0) G[g] = s;
    }
    __syncthreads();
    if (wv == 0) {
      unsigned long long pf = w_pfx(G[lane], lane);
      int L = __ffsll(__ballot(pf > sc.T)) - 1;
      unsigned long long excl = (L > 0) ? __shfl(pf, L - 1) : 0ull;
      if (lane == 0) { sc.selg = L; sc.resid = sc.T - excl; }
    }
    __syncthreads();
    if (wv == 0) {
      int g = sc.selg;
      unsigned long long pf = w_pfx(sh.f.H[g * 64 + lane], lane);
      int L = __ffsll(__ballot(pf > sc.resid)) - 1;
      unsigned long long excl = (L > 0) ? __shfl(pf, L - 1) : 0ull;
      if (lane == 0) { sc.b0c = g * 64 + L; sc.resid = sc.resid - excl; }
    }
    __syncthreads();
    // ---- L1 sum ----
    for (int i = tid; i < 1024; i += FTPB) sh.f.H1[i] = 0ull;
    __syncthreads();
    {
      const unsigned b0 = sc.b0c;
      FOR_CANDS(e, {
        unsigned key = (unsigned)(e >> 32);
        if ((key >> 20) == b0)
          atomicAdd(&sh.f.H1[(key >> 10) & 1023u], w_efix(key, maxv, r));
      });
    }
    __syncthreads();
    {
      unsigned long long s = w_red(sh.f.H1[wv * 64 + lane]);
      if (lane == 0) G[wv] = s;
    }
    __syncthreads();
    if (wv == 0) {
      unsigned long long gv = (lane < 16) ? G[lane] : 0ull;
      unsigned long long pf = w_pfx(gv, lane);
      int L = __ffsll(__ballot((lane < 16) && (pf > sc.resid))) - 1;
      unsigned long long excl = (L > 0) ? __shfl(pf, L - 1) : 0ull;
      if (lane == 0) { sc.selg = L; sc.resid = sc.resid - excl; }
    }
    __syncthreads();
    if (wv == 0) {
      int g = sc.selg;
      unsigned long long pf = w_pfx(sh.f.H1[g * 64 + lane], lane);
      int L = __ffsll(__ballot(pf > sc.resid)) - 1;
      unsigned long long excl = (L > 0) ? __shfl(pf, L - 1) : 0ull;
      if (lane == 0) { sc.b1c = g * 64 + L; sc.resid = sc.resid - excl; }
    }
    __syncthreads();
    // ---- L2 sum -> crossing key ----
    for (int i = tid; i < 1024; i += FTPB) sh.f.H1[i] = 0ull;
    __syncthreads();
    {
      const unsigned pref = (sc.b0c << 10) | sc.b1c;
      FOR_CANDS(e, {
        unsigned key = (unsigned)(e >> 32);
        if ((key >> 10) == pref)
          atomicAdd(&sh.f.H1[key & 1023u], w_efix(key, maxv, r));
      });
    }
    __syncthreads();
    {
      unsigned long long s = w_red(sh.f.H1[wv * 64 + lane]);
      if (lane == 0) G[wv] = s;
    }
    __syncthreads();
    if (wv == 0) {
      unsigned long long gv = (lane < 16) ? G[lane] : 0ull;
      unsigned long long pf = w_pfx(gv, lane);
      int L = __ffsll(__ballot((lane < 16) && (pf > sc.resid))) - 1;
      unsigned long long excl = (L > 0) ? __shfl(pf, L - 1) : 0ull;
      if (lane == 0) { sc.selg = L; sc.resid = sc.resid - excl; }
    }
    __syncthreads();
    if (wv == 0) {
      int g = sc.selg;
      unsigned long long pf = w_pfx(sh.f.H1[g * 64 + lane], lane);
      int L = __ffsll(__ballot(pf > sc.resid)) - 1;
      unsigned long long excl = (L > 0) ? __shfl(pf, L - 1) : 0ull;
      if (lane == 0) {
        sc.kc = (sc.b0c << 20) | (sc.b1c << 10) | (unsigned)(g * 64 + L);
        sc.resid = sc.resid - excl;
      }
    }
    __syncthreads();
    const unsigned kc = sc.kc;
    {
      unsigned long long ek = w_efix(kc, maxv, r);
      if (tid == 0) {
        if (ek == 0ull) sc.flag = 1u;
        else sc.mreq = (unsigned)(sc.resid / ek + 1ull);
        sc.tcnt = 0u;
      }
    }
    __syncthreads();
    if (sc.flag) break;
    // ---- tie group at kc: pick mreq-th smallest index ----
    FOR_CANDS(e, {
      if ((unsigned)(e >> 32) == kc) {
        unsigned pos = atomicAdd(&sc.tcnt, 1u);
        if (pos < 256u) tieidx[pos] = (unsigned)(e & 0xFFFFFFFFu);
      }
    });
    __syncthreads();
    const unsigned t = sc.tcnt;
    if (t > 256u || sc.mreq > t) {
      if (tid == 0) sc.flag = 1u;
      __syncthreads();
      break;
    }
    if (tid < (int)t) {
      unsigned my = tieidx[tid];
      unsigned rank = 0;
      for (unsigned j = 0; j < t; ++j) rank += (tieidx[j] < my) ? 1u : 0u;
      if (rank == sc.mreq - 1u) sc.cutidx = my;
    }
    __syncthreads();
    // ---- scatter-correct candidate positions only ----
    const unsigned long long cutoff =
        ((unsigned long long)kc << 32) | sc.cutidx;
    FOR_CANDS(e, {
      unsigned key = (unsigned)(e >> 32);
      unsigned idx = (unsigned)(e & 0xFFFFFFFFu);
      orow[idx] = (e >= cutoff) ? w_dualfinite(w_key2f(key) * r) : NEG;
    });
    return;
  } while (0);
#undef FOR_CANDS

  // ============ exact fallback (rare/adversarial): full-row rewrite ========
  {
    const float4* l4 =
        reinterpret_cast<const float4*>(logits + (size_t)row * (size_t)V);
    const int V4 = V >> 2;
    unsigned prefix = 0;
    int kk = k;
    for (int lvl = 0; lvl < 3; ++lvl) {
      const int shift = (lvl == 0) ? 20 : (lvl == 1) ? 8 : 0;
      const int nb = (lvl == 2) ? 256 : 4096;
      for (int i = tid; i < 2 * WNB; i += FTPB) sh.fb.u.sel[i] = 0;
      __syncthreads();
      if (lvl == 0) {
        for (int i = tid; i < V4; i += FTPB) {
          float4 v = l4[i];
          atomicAdd(&sh.fb.u.sel[w_f2key(v.x) >> 20], 1u);
          atomicAdd(&sh.fb.u.sel[w_f2key(v.y) >> 20], 1u);
          atomicAdd(&sh.fb.u.sel[w_f2key(v.z) >> 20], 1u);
          atomicAdd(&sh.fb.u.sel[w_f2key(v.w) >> 20], 1u);
        }
      } else {
        const int hs = (lvl == 1) ? 20 : 8;
        const unsigned want = prefix >> hs;
        const unsigned bmask = (unsigned)(nb - 1);
        for (int i = tid; i < V4; i += FTPB) {
          float4 v = l4[i];
          unsigned key;
          key = w_f2key(v.x);
          if ((key >> hs) == want) atomicAdd(&sh.fb.u.sel[(key >> shift) & bmask], 1u);
          key = w_f2key(v.y);
          if ((key >> hs) == want) atomicAdd(&sh.fb.u.sel[(key >> shift) & bmask], 1u);
          key = w_f2key(v.z);
          if ((key >> hs) == want) atomicAdd(&sh.fb.u.sel[(key >> shift) & bmask], 1u);
          key = w_f2key(v.w);
          if ((key >> hs) == want) atomicAdd(&sh.fb.u.sel[(key >> shift) & bmask], 1u);
        }
      }
      __syncthreads();
      if (tid == 0) {
        int acc = 0;
        sh_prefix = prefix;
        sh_kk = kk;
        for (int b = nb - 1; b >= 0; --b) {
          int h = (int)sh.fb.u.sel[b];
          if (acc + h >= kk) {
            sh_kk = kk - acc;
            sh_prefix = prefix | ((unsigned)b << shift);
            break;
          }
          acc += h;
        }
      }
      __syncthreads();
      prefix = sh_prefix;
      kk = sh_kk;
      __syncthreads();
      if (lvl == 2) break;
      if (tid == 0) s_cnt = 0;
      __syncthreads();
      for (int i = tid; i < V4; i += FTPB) {
        float4 v = l4[i];
        unsigned c = (w_f2key(v.x) >= prefix) + (w_f2key(v.y) >= prefix) +
                     (w_f2key(v.z) >= prefix) + (w_f2key(v.w) >= prefix);
        if (c) atomicAdd(&s_cnt, c);
      }
      __syncthreads();
      if (s_cnt <= (unsigned)WBUF) break;
      __syncthreads();
    }
    const unsigned thr = prefix;

    if (tid == 0) s_cnt = 0;
    __syncthreads();
    for (int i = tid; i < V4; i += FTPB) {
      float4 v = l4[i];
      const unsigned basei = (unsigned)(i << 2);
      unsigned key;
      key = w_f2key(v.x);
      if (key >= thr) {
        unsigned pos = atomicAdd(&s_cnt, 1u);
        if (pos < WBUF) sh.fb.u.buf[pos] = ((unsigned long long)key << 32) | basei;
      }
      key = w_f2key(v.y);
      if (key >= thr) {
        unsigned pos = atomicAdd(&s_cnt, 1u);
        if (pos < WBUF)
          sh.fb.u.buf[pos] = ((unsigned long long)key << 32) | (basei + 1u);
      }
      key = w_f2key(v.z);
      if (key >= thr) {
        unsigned pos = atomicAdd(&s_cnt, 1u);
        if (pos < WBUF)
          sh.fb.u.buf[pos] = ((unsigned long long)key << 32) | (basei + 2u);
      }
      key = w_f2key(v.w);
      if (key >= thr) {
        unsigned pos = atomicAdd(&s_cnt, 1u);
        if (pos < WBUF)
          sh.fb.u.buf[pos] = ((unsigned long long)key << 32) | (basei + 3u);
      }
    }
    __syncthreads();
    int nn = (int)s_cnt;
    if (nn > WBUF) nn = WBUF;
    if (nn < 1) nn = 1;

    int m = 64;
    while (m < nn) m <<= 1;
    for (int i = nn + tid; i < m; i += FTPB)
      sh.fb.u.buf[i] = 0xFFFFFFFFFFFFFFFFull;
    __syncthreads();
    for (int size = 2; size <= m; size <<= 1) {
      for (int stride = size >> 1; stride > 0; stride >>= 1) {
        if (stride >= 32) __syncthreads();
        else __asm__ volatile("" ::: "memory");
        for (int i = tid; i < m; i += FTPB) {
          int j = i ^ stride;
          if (j > i) {
            unsigned long long a = sh.fb.u.buf[i], bb = sh.fb.u.buf[j];
            bool up = ((i & size) == 0);
            if (up ? (a > bb) : (a < bb)) { sh.fb.u.buf[i] = bb; sh.fb.u.buf[j] = a; }
          }
        }
      }
    }
    __syncthreads();

    const float maxv = w_key2f((unsigned)(sh.fb.u.buf[nn - 1] >> 32)) * r;
    const int i0 = tid << 2;
    float e0 = 0.f, e1 = 0.f, e2 = 0.f, e3 = 0.f;
    if (i0 < nn)
      e0 = expf(w_key2f((unsigned)(sh.fb.u.buf[i0] >> 32)) * r - maxv);
    if (i0 + 1 < nn)
      e1 = expf(w_key2f((unsigned)(sh.fb.u.buf[i0 + 1] >> 32)) * r - maxv);
    if (i0 + 2 < nn)
      e2 = expf(w_key2f((unsigned)(sh.fb.u.buf[i0 + 2] >> 32)) * r - maxv);
    if (i0 + 3 < nn)
      e3 = expf(w_key2f((unsigned)(sh.fb.u.buf[i0 + 3] >> 32)) * r - maxv);
    const float lsum = e0 + e1 + e2 + e3;
    float vincl = lsum;
    for (int d = 1; d < 64; d <<= 1) {
      float o = __shfl_up(vincl, d);
      if (lane >= d) vincl += o;
    }
    if (lane == 63) wsum[wv] = vincl;
    __syncthreads();
    if (wv == 0 && lane < 16) {
      float s = wsum[lane];
      for (int d = 1; d < 16; d <<= 1) {
        float o = __shfl_up(s, d);
        if (lane >= d) s += o;
      }
      wsum[lane] = s;
    }
    __syncthreads();
    {
      float rr = (wv > 0 ? wsum[wv - 1] : 0.0f) + (vincl - lsum);
      rr += e0; if (i0 < nn)     sh.fb.csum[i0] = rr;
      rr += e1; if (i0 + 1 < nn) sh.fb.csum[i0 + 1] = rr;
      rr += e2; if (i0 + 2 < nn) sh.fb.csum[i0 + 2] = rr;
      rr += e3; if (i0 + 3 < nn) sh.fb.csum[i0 + 3] = rr;
    }
    __syncthreads();

    const int k_eff = (k < nn) ? k : nn;
    const unsigned vkey = (unsigned)(sh.fb.u.buf[nn - k_eff] >> 32);
    if (tid == 0) { s_j0 = 0; s_c = nn - 1; }
    __syncthreads();
    for (int i = tid; i < nn; i += FTPB) {
      unsigned ki = (unsigned)(sh.fb.u.buf[i] >> 32);
      if (ki == vkey && (i == 0 || (unsigned)(sh.fb.u.buf[i - 1] >> 32) != vkey))
        s_j0 = i;
    }
    __syncthreads();
    const int j0 = s_j0;
    const float base = (j0 > 0) ? sh.fb.csum[j0 - 1] : 0.0f;
    const float Z = sh.fb.csum[nn - 1] - base;
    const float thrp = (1.0f - p) * Z;
    for (int i = j0 + tid; i < nn; i += FTPB) {
      if (sh.fb.csum[i] - base > thrp) atomicMin(&s_c, i);
    }
    __syncthreads();
    const unsigned long long cutoff = sh.fb.u.buf[s_c];

    // full-row rewrite (the NEG prefill may be wrong when cutoff < T0)
    float4* o4 = reinterpret_cast<float4*>(orow);
    for (int i = tid; i < V4; i += FTPB) {
      float4 v = l4[i];
      const unsigned e = (unsigned)(i << 2);
      unsigned long long k0 = ((unsigned long long)w_f2key(v.x) << 32) | e;
      unsigned long long k1 = ((unsigned long long)w_f2key(v.y) << 32) | (e + 1u);
      unsigned long long k2 = ((unsigned long long)w_f2key(v.z) << 32) | (e + 2u);
      unsigned long long k3 = ((unsigned long long)w_f2key(v.w) << 32) | (e + 3u);
      v.x = (k0 >= cutoff) ? w_dualfinite(v.x * r) : NEG;
      v.y = (k1 >= cutoff) ? w_dualfinite(v.y * r) : NEG;
      v.z = (k2 >= cutoff) ? w_dualfinite(v.z * r) : NEG;
      v.w = (k3 >= cutoff) ? w_dualfinite(v.w * r) : NEG;
      o4[i] = v;
    }
  }
}

extern "C" void kernel_launch(void* const* d_in, const int* in_sizes, int n_in,
                              void* d_out, int out_size, void* d_ws, size_t ws_size,
                              hipStream_t stream) {
  const float* logits = (const float*)d_in[0];
  const float* temps  = (const float*)d_in[1];
  const int*   ks     = (const int*)d_in[2];
  const float* ps     = (const float*)d_in[3];
  float* out = (float*)d_out;

  const int B = in_sizes[1];
  const int V = in_sizes[0] / B;
  const int V4 = V >> 2;

  // d_ws: cnt[B*WCPAD] u32 | gcand[B*WBUF] u64
  unsigned* cnt = (unsigned*)d_ws;
  unsigned long long* gcand =
      (unsigned long long*)(cnt + (size_t)B * WCPAD);

  dim3 gg(WSB, B);
  g15_gather<<<gg, GTPB, 0, stream>>>(logits, out, cnt, gcand, V4);
  g15_finish<<<B, FTPB, 0, stream>>>(logits, gcand, cnt, temps, ks, ps, out, V);
}